// Round 10
// baseline (425.615 us; speedup 1.0000x reference)
//
#include <hip/hip_runtime.h>
#include <cstdint>
#include <cstddef>

typedef __bf16  bf16x8 __attribute__((ext_vector_type(8)));
typedef float   f32x4  __attribute__((ext_vector_type(4)));
typedef unsigned short u16x8 __attribute__((ext_vector_type(8)));
typedef unsigned short u16x4 __attribute__((ext_vector_type(4)));

#define B_SZ  4096
#define SEQ   9
#define CDIM  768
#define HEADS 12
#define DH    64
#define MROWS (B_SZ*SEQ)      // 36864
#define NQKV  (3*CDIM)        // 2304
#define NPAIR (B_SZ*HEADS)    // 49152
#define GK    768             // K for both GEMMs
#define NTK   12              // K-tiles for 256^2 kernel (GK/64)
#define NT2   24              // K-tiles for 256x128 kernel (GK/32)

#define AS1 __attribute__((address_space(1)))
#define AS3 __attribute__((address_space(3)))

__device__ inline float b2f(unsigned short u){
  union{unsigned i; float f;} x; x.i = ((unsigned)u)<<16; return x.f;
}
__device__ inline unsigned short f2b(float f){ // RNE fp32->bf16
  unsigned x = __float_as_uint(f);
  return (unsigned short)((x + 0x7fffu + ((x>>16)&1u)) >> 16);
}

// ======= fused prep: x->bf16, LDS-tiled Wq^T, Wp^T, table — 1 launch =======
#define CONV_BLKS (MROWS*CDIM/1024)          // 27648
#define TCQ_BLKS  ((CDIM/64)*(NQKV/64))      // 432
#define TCP_BLKS  ((CDIM/64)*(CDIM/64))      // 144
#define PREP_BLKS (CONV_BLKS+TCQ_BLKS+TCP_BLKS+1)  // 28225

__device__ inline void tconv_tile(const float* __restrict__ in,
                                  unsigned short* __restrict__ out,
                                  int R, int C, int tr, int tc,
                                  float (*tl)[65], int tid){
  int r0 = tr*64, c0 = tc*64;
  int lr = tid >> 4, lc = (tid & 15)*4;
  #pragma unroll
  for (int p=0;p<4;++p){
    float4 v = *(const float4*)(&in[(size_t)(r0+lr+p*16)*C + c0+lc]);
    tl[lr+p*16][lc]=v.x; tl[lr+p*16][lc+1]=v.y; tl[lr+p*16][lc+2]=v.z; tl[lr+p*16][lc+3]=v.w;
  }
  __syncthreads();
  #pragma unroll
  for (int p=0;p<4;++p){
    int oc = lr+p*16;
    u16x4 o;
    o.x = f2b(tl[lc+0][oc]); o.y = f2b(tl[lc+1][oc]);
    o.z = f2b(tl[lc+2][oc]); o.w = f2b(tl[lc+3][oc]);
    *(u16x4*)(&out[(size_t)(c0+oc)*R + r0 + lc]) = o;
  }
}

__global__ __launch_bounds__(256) void k_prep(const float* __restrict__ x,
                                              unsigned short* __restrict__ xb,
                                              const float* __restrict__ Wq,
                                              unsigned short* __restrict__ Wq_t,
                                              const float* __restrict__ Wp,
                                              unsigned short* __restrict__ Wp_t,
                                              float* __restrict__ cs,
                                              float* __restrict__ sn){
  __shared__ float tl[64][65];
  int blk = blockIdx.x, tid = threadIdx.x;
  if (blk < CONV_BLKS){
    int t = blk*256 + tid;
    float4 v = ((const float4*)x)[t];
    u16x4 o; o.x=f2b(v.x); o.y=f2b(v.y); o.z=f2b(v.z); o.w=f2b(v.w);
    ((u16x4*)xb)[t] = o;
  } else if (blk < CONV_BLKS+TCQ_BLKS){
    int b2 = blk - CONV_BLKS;
    tconv_tile(Wq, Wq_t, CDIM, NQKV, b2/36, b2%36, tl, tid);
  } else if (blk < CONV_BLKS+TCQ_BLKS+TCP_BLKS){
    int b3 = blk - CONV_BLKS - TCQ_BLKS;
    tconv_tile(Wp, Wp_t, CDIM, CDIM, b3/12, b3%12, tl, tid);
  } else {
    for (int t=tid; t<SEQ*DH; t+=256){
      const float blo[9] = {1.f,4.f,8.f,10.f,12.f,30.f,1.f,8.f,1.f};
      const float bhi[9] = {4.f,8.f,10.f,12.f,30.f,45.f,8.f,30.f,45.f};
      int n = t / DH, d = t - n*DH;
      int f = (d < 32) ? (d>>1) : ((d-32)>>1);
      float freq = 3.14159265358979f * (1.0f + (4.0f/15.0f)*(float)f);
      float band = (d < 32) ? blo[n] : bhi[n];
      float ang = band * freq;
      cs[t] = cosf(ang);
      sn[t] = sinf(ang);
    }
  }
}

// ---- shared GEMM phase machinery ----
#define GLOAD(SRC, LDSOFF) \
  __builtin_amdgcn_global_load_lds((const AS1 void*)(SRC), \
      (AS3 void*)(smem + (LDSOFF) + (w<<10)), 16, 0, 0)

#define PHASE_MID  do{ __builtin_amdgcn_s_barrier(); \
  asm volatile("s_waitcnt lgkmcnt(0)" ::: "memory"); \
  __builtin_amdgcn_sched_barrier(0); \
  __builtin_amdgcn_s_setprio(1); }while(0)
#define PHASE_END  do{ __builtin_amdgcn_s_setprio(0); \
  __builtin_amdgcn_s_barrier(); }while(0)

// ====== GEMM1: 256x256, BK=64, 4 balanced phases per K-tile (R4 best) ======
#define RD_A(SLOT, H) do{ _Pragma("unroll") \
  for (int m=0;m<4;++m) aQ[m] = *(const bf16x8*)((SLOT) + aRd + ((H)*4+m)*1024); }while(0)
#define RD_B(SLOT) do{ _Pragma("unroll") \
  for (int n=0;n<4;++n) bR[n] = *(const bf16x8*)((SLOT) + bRd + n*1024); }while(0)
#define MFMA_Q(H) do{ _Pragma("unroll") \
  for (int m=0;m<4;++m){ _Pragma("unroll") \
    for (int n=0;n<4;++n) \
      acc[(H)*4+m][n] = __builtin_amdgcn_mfma_f32_16x16x32_bf16(aQ[m], bR[n], acc[(H)*4+m][n], 0,0,0); } }while(0)

#define TILE_BODY(T, DB) do{ \
  const char* aS0 = smem + (DB)*16384; \
  const char* aS1 = smem + ((DB)+1)*16384; \
  const char* bS0 = smem + 65536 + (DB)*16384; \
  const char* bS1 = smem + 65536 + ((DB)+1)*16384; \
  int u1=(T)+1; if(u1>NTK-1)u1=NTK-1; int u2=(T)+2; if(u2>NTK-1)u2=NTK-1; \
  size_t o1=(size_t)u1*64+32, o2a=(size_t)u2*64, o2b=o2a+32; \
  /* P1: A mi0-3 k0, B k0; stage B1(t+1) */ \
  RD_A(aS0,0); RD_B(bS0); \
  GLOAD(bSrc0+o1, 65536 + (3-(DB))*16384); \
  GLOAD(bSrc1+o1, 65536 + (3-(DB))*16384 + 8192); \
  PHASE_MID; MFMA_Q(0); PHASE_END; \
  /* P2: A mi4-7 k0; stage A0(t+2) */ \
  RD_A(aS0,1); \
  GLOAD(aSrc0+o2a, (DB)*16384); \
  GLOAD(aSrc1+o2a, (DB)*16384 + 8192); \
  PHASE_MID; MFMA_Q(1); PHASE_END; \
  /* P3: A mi0-3 k1, B k1; stage B0(t+2) */ \
  RD_A(aS1,0); RD_B(bS1); \
  GLOAD(bSrc0+o2a, 65536 + (DB)*16384); \
  GLOAD(bSrc1+o2a, 65536 + (DB)*16384 + 8192); \
  PHASE_MID; MFMA_Q(0); PHASE_END; \
  /* P4: A mi4-7 k1; stage A1(t+2); vmcnt(6) */ \
  RD_A(aS1,1); \
  GLOAD(aSrc0+o2b, ((DB)+1)*16384); \
  GLOAD(aSrc1+o2b, ((DB)+1)*16384 + 8192); \
  PHASE_MID; MFMA_Q(1); \
  __builtin_amdgcn_s_setprio(0); \
  asm volatile("s_waitcnt vmcnt(6)" ::: "memory"); \
  __builtin_amdgcn_s_barrier(); }while(0)

template<int WRITE_F32>
__global__ __launch_bounds__(512, 2) void k_gemm8p(const unsigned short* __restrict__ A,
                                                   const unsigned short* __restrict__ Bt,
                                                   void* __restrict__ Cout,
                                                   const float* __restrict__ bias,
                                                   int M, int N, int NTN, int NWG){
  __shared__ char smem[131072];   // A ring 4x16KB | B ring 4x16KB
  int wg = blockIdx.x;
  int cpx = NWG >> 3;
  int swz = (wg & 7)*cpx + (wg >> 3);          // bijective (NWG%8==0)
  int bm = swz / NTN, bn = swz - bm*NTN;
  int m0 = bm << 8, n0 = bn << 8;

  int tid = threadIdx.x;
  int w = tid >> 6, lane = tid & 63;
  int r = lane & 15, g4 = lane >> 4;
  int wr = w >> 2, wc = w & 3;

  // st_16x32 read-side: 16B-granule g4 ^= 2*row_bit3 (verified 0-conflict)
  int seg = g4 ^ (((r >> 3) & 1) << 1);
  int aRd = (wr*128 + r)*64 + seg*16;
  int bRd = (wc*64  + r)*64 + seg*16;

  // staging side (pre-swizzled global source; linear LDS dest)
  int srow = tid >> 2;
  int gsw  = (tid & 3) ^ (((tid >> 5) & 1) << 1);
  const unsigned short* aSrc0 = A  + (size_t)(m0 + srow)*GK + gsw*8;
  const unsigned short* aSrc1 = aSrc0 + (size_t)128*GK;
  const unsigned short* bSrc0 = Bt + (size_t)(n0 + srow)*GK + gsw*8;
  const unsigned short* bSrc1 = bSrc0 + (size_t)128*GK;

  const f32x4 fz = {0.f,0.f,0.f,0.f};
  f32x4 acc[8][4];
  #pragma unroll
  for (int mi=0;mi<8;++mi)
    #pragma unroll
    for (int ni=0;ni<4;++ni) acc[mi][ni] = fz;
  bf16x8 aQ[4], bR[4];

  // ---- prologue: 7 half-tiles ----
  GLOAD(aSrc0+ 0,     0); GLOAD(aSrc1+ 0,  8192);
  GLOAD(bSrc0+ 0, 65536); GLOAD(bSrc1+ 0, 65536+ 8192);
  GLOAD(aSrc0+32, 16384); GLOAD(aSrc1+32, 16384+8192);
  GLOAD(bSrc0+32, 65536+16384); GLOAD(bSrc1+32, 65536+16384+8192);
  GLOAD(aSrc0+64, 32768); GLOAD(aSrc1+64, 32768+8192);
  GLOAD(bSrc0+64, 65536+32768); GLOAD(bSrc1+64, 65536+32768+8192);
  GLOAD(aSrc0+96, 49152); GLOAD(aSrc1+96, 49152+8192);
  asm volatile("s_waitcnt vmcnt(6)" ::: "memory");
  __builtin_amdgcn_s_barrier();

  #pragma unroll 1
  for (int tt=0; tt<NTK; tt+=2){
    TILE_BODY(tt,   0);
    TILE_BODY(tt+1, 2);
  }
  asm volatile("s_waitcnt vmcnt(0)" ::: "memory");

  // ---- epilogue: C/D layout col=lane&15, row=(lane>>4)*4+q ----
  if (WRITE_F32){
    #pragma unroll
    for (int mi=0;mi<8;++mi){
      #pragma unroll
      for (int ni=0;ni<4;++ni){
        int col = n0 + wc*64 + ni*16 + r;
        float bb = bias ? bias[col] : 0.f;
        #pragma unroll
        for (int q=0;q<4;++q){
          int row = m0 + wr*128 + mi*16 + g4*4 + q;
          ((float*)Cout)[(size_t)row*N + col] = acc[mi][ni][q] + bb;
        }
      }
    }
  } else {
    // head-major qkv: idx = ((b*12+h)*9+i)*192 + which*64 + d
    #pragma unroll
    for (int mi=0;mi<8;++mi){
      #pragma unroll
      for (int q=0;q<4;++q){
        int row = m0 + wr*128 + mi*16 + g4*4 + q;
        int bb = row / 9;
        int ii = row - bb*9;
        size_t rb = (size_t)bb*HEADS;
        #pragma unroll
        for (int ni=0;ni<4;++ni){
          int col = n0 + wc*64 + ni*16 + r;
          int which = (col >= 1536) ? 2 : (col >= 768 ? 1 : 0);
          int rem = col - which*768;
          int h = rem >> 6, d = rem & 63;
          size_t idx = ((rb + h)*9 + ii)*192 + which*64 + d;
          ((unsigned short*)Cout)[idx] = f2b(acc[mi][ni][q]);
        }
      }
    }
  }
}

// ============ GEMM2: 256x128, BK=32, 3-slot ring, 2 blocks/CU ============
#define TILE2(T, SL, SP) do{ \
  const char* aS = smem + (SL)*16384; \
  const char* bS = smem + 49152 + (SL)*8192; \
  int u2=(T)+2; if(u2>NT2-1)u2=NT2-1; size_t o2=(size_t)u2*32; \
  _Pragma("unroll") for (int m=0;m<4;++m) aQ[m] = *(const bf16x8*)(aS + aRd + m*1024); \
  _Pragma("unroll") for (int n=0;n<4;++n) bR[n] = *(const bf16x8*)(bS + bRd + n*1024); \
  GLOAD(aSrc0+o2, (SP)*16384); \
  GLOAD(aSrc1+o2, (SP)*16384 + 8192); \
  GLOAD(bSrc +o2, 49152 + (SP)*8192); \
  PHASE_MID; \
  _Pragma("unroll") for (int m=0;m<4;++m){ _Pragma("unroll") for (int n=0;n<4;++n) \
    acc[m][n] = __builtin_amdgcn_mfma_f32_16x16x32_bf16(aQ[m], bR[n], acc[m][n], 0,0,0); } \
  __builtin_amdgcn_s_setprio(0); \
  asm volatile("s_waitcnt vmcnt(3)" ::: "memory"); \
  __builtin_amdgcn_s_barrier(); }while(0)

__global__ __launch_bounds__(512, 4) void k_gemm2b(const unsigned short* __restrict__ A,
                                                   const unsigned short* __restrict__ Bt,
                                                   float* __restrict__ C,
                                                   const float* __restrict__ bias,
                                                   int M, int N, int NTN, int NWG){
  __shared__ char smem[73728];   // A 3x16KB | B 3x8KB
  int wg = blockIdx.x;
  int cpx = NWG >> 3;
  int swz = (wg & 7)*cpx + (wg >> 3);
  int bm = swz / NTN, bn = swz - bm*NTN;
  int m0 = bm << 8, n0 = bn << 7;

  int tid = threadIdx.x;
  int w = tid >> 6, lane = tid & 63;
  int r = lane & 15, g4 = lane >> 4;
  int wr = w >> 1, wc = w & 1;

  int seg = g4 ^ (((r >> 3) & 1) << 1);
  int aRd = (wr*64 + r)*64 + seg*16;
  int bRd = (wc*64 + r)*64 + seg*16;

  int srow = tid >> 2;
  int gsw  = (tid & 3) ^ (((tid >> 5) & 1) << 1);
  const unsigned short* aSrc0 = A  + (size_t)(m0 + srow)*GK + gsw*8;
  const unsigned short* aSrc1 = aSrc0 + (size_t)128*GK;
  const unsigned short* bSrc  = Bt + (size_t)(n0 + srow)*GK + gsw*8;

  const f32x4 fz = {0.f,0.f,0.f,0.f};
  f32x4 acc[4][4];
  #pragma unroll
  for (int m=0;m<4;++m)
    #pragma unroll
    for (int n=0;n<4;++n) acc[m][n] = fz;
  bf16x8 aQ[4], bR[4];

  GLOAD(aSrc0+ 0, 0);     GLOAD(aSrc1+ 0, 8192);       GLOAD(bSrc+ 0, 49152);
  GLOAD(aSrc0+32, 16384); GLOAD(aSrc1+32, 16384+8192); GLOAD(bSrc+32, 49152+8192);
  asm volatile("s_waitcnt vmcnt(3)" ::: "memory");
  __builtin_amdgcn_s_barrier();

  #pragma unroll 1
  for (int tt=0; tt<NT2; tt+=3){
    TILE2(tt,   0, 2);
    TILE2(tt+1, 1, 0);
    TILE2(tt+2, 2, 1);
  }
  asm volatile("s_waitcnt vmcnt(0)" ::: "memory");

  #pragma unroll
  for (int mi=0;mi<4;++mi){
    #pragma unroll
    for (int ni=0;ni<4;++ni){
      int col = n0 + wc*64 + ni*16 + r;
      float bb = bias ? bias[col] : 0.f;
      #pragma unroll
      for (int q=0;q<4;++q){
        int row = m0 + wr*64 + mi*16 + g4*4 + q;
        C[(size_t)row*N + col] = acc[mi][ni][q] + bb;
      }
    }
  }
}

// ========= dRoFE + attention v5: bulk-coalesced LDS staging =========
// Block: 192 thr (3 waves), PPB2=21 pairs. Whole qkv region (21*3456 B,
// contiguous in head-major layout) is staged via coalesced uint4 loads +
// rotation-swizzled ds_write: granule g of row r stored at (g+r)%24.
// Bank math: compute reads (lanes=distinct rows, same g) hit bank group
// (g+r) mod 8 -> all 8 groups covered -> balanced. K roped in-place.
#define PPB2 21
__global__ __launch_bounds__(192) void k_attn(const unsigned short* __restrict__ qkv,
                                              const float* __restrict__ demo,
                                              const float* __restrict__ cs,
                                              const float* __restrict__ sn,
                                              unsigned short* __restrict__ out){
  __shared__ __align__(16) unsigned int kvs[PPB2*SEQ*96];   // 72576 B
  __shared__ float s_cs[SEQ*DH], s_sn[SEQ*DH];
  int tid = threadIdx.x;
  for (int t=tid; t<SEQ*DH; t+=192){ s_cs[t]=cs[t]; s_sn[t]=sn[t]; }

  int pair0 = blockIdx.x*PPB2;
  int npairs = NPAIR - pair0; if (npairs > PPB2) npairs = PPB2;
  int nchunk = npairs*216;               // 16B chunks in region

  // ---- bulk stage: coalesced global reads, swizzled LDS writes ----
  const uint4* src = (const uint4*)(qkv + (size_t)pair0*(SEQ*192));
  for (int c = tid; c < nchunk; c += 192){
    uint4 v = src[c];
    int row = c/24, g = c - row*24;
    int rm = row % 24;
    int gp = g + rm; if (gp >= 24) gp -= 24;
    *(uint4*)(&kvs[row*96 + gp*4]) = v;
  }
  __syncthreads();                       // region staged

  int pr = tid / 9, i = tid - pr*9;
  bool act = (pr < npairs);
  int b = 0, h = 0; float age = 0.f, gen = 0.f;
  if (act){
    int pair = pair0 + pr;
    b = pair / HEADS; h = pair - b*HEADS;
    age = demo[2*b]; gen = demo[2*b+1];
  }

  // ---- rope Q (into regs) + rope K (in place, own row) ----
  float qr[64];
  int r_own = pr*9 + i;
  int rm_own = r_own % 24;
  if (act){
    #pragma unroll
    for (int t8=0;t8<8;++t8){
      int gq = t8 + rm_own;      if (gq >= 24) gq -= 24;
      int gk = t8 + 8 + rm_own;  if (gk >= 24) gk -= 24;
      uint4 qv = *(const uint4*)(&kvs[r_own*96 + gq*4]);
      uint4 kw = *(const uint4*)(&kvs[r_own*96 + gk*4]);
      unsigned int kp[4];
      const unsigned int qa[4] = {qv.x, qv.y, qv.z, qv.w};
      const unsigned int ka[4] = {kw.x, kw.y, kw.z, kw.w};
      #pragma unroll
      for (int p2=0;p2<4;++p2){
        int d = t8*8 + p2*2;
        float c0=s_cs[i*64+d], s0=s_sn[i*64+d];
        float c1=s_cs[i*64+d+1], s1=s_sn[i*64+d+1];
        float q0=b2f((unsigned short)(qa[p2]&0xffffu)), q1=b2f((unsigned short)(qa[p2]>>16));
        qr[d]   = age*q0*c0 - gen*q1*s0;
        qr[d+1] = age*q1*c1 + gen*q0*s1;
        float k0=b2f((unsigned short)(ka[p2]&0xffffu)), k1=b2f((unsigned short)(ka[p2]>>16));
        float r0 = age*k0*c0 - gen*k1*s0;
        float r1 = age*k1*c1 + gen*k0*s1;
        kp[p2] = (unsigned)f2b(r0) | ((unsigned)f2b(r1)<<16);
      }
      uint4 kv4; kv4.x=kp[0]; kv4.y=kp[1]; kv4.z=kp[2]; kv4.w=kp[3];
      *(uint4*)(&kvs[r_own*96 + gk*4]) = kv4;
    }
  }
  __syncthreads();                       // roped K visible to all

  if (!act) return;

  // ---- scores ----
  float s[9]; float mx = -1e30f;
  #pragma unroll
  for (int j=0;j<9;++j){
    int rj = pr*9 + j;
    int rmj = rj % 24;
    float acc = 0.f;
    #pragma unroll
    for (int t8=0;t8<8;++t8){
      int gk = t8 + 8 + rmj; if (gk >= 24) gk -= 24;
      uint4 kk = *(const uint4*)(&kvs[rj*96 + gk*4]);
      acc += qr[t8*8+0]*b2f((unsigned short)(kk.x&0xffffu)) + qr[t8*8+1]*b2f((unsigned short)(kk.x>>16));
      acc += qr[t8*8+2]*b2f((unsigned short)(kk.y&0xffffu)) + qr[t8*8+3]*b2f((unsigned short)(kk.y>>16));
      acc += qr[t8*8+4]*b2f((unsigned short)(kk.z&0xffffu)) + qr[t8*8+5]*b2f((unsigned short)(kk.z>>16));
      acc += qr[t8*8+6]*b2f((unsigned short)(kk.w&0xffffu)) + qr[t8*8+7]*b2f((unsigned short)(kk.w>>16));
    }
    s[j] = acc * 0.125f;
    mx = fmaxf(mx, s[j]);
  }
  float den = 0.f;
  #pragma unroll
  for (int j=0;j<9;++j){ s[j] = __expf(s[j]-mx); den += s[j]; }
  float inv = 1.f/den;
  #pragma unroll
  for (int j=0;j<9;++j) s[j] *= inv;

  // ---- PV in two 32-dim halves ----
  unsigned short* op = out + (size_t)(b*SEQ+i)*CDIM + h*DH;
  #pragma unroll
  for (int hf=0; hf<2; ++hf){
    float o[32];
    #pragma unroll
    for (int d=0;d<32;++d) o[d]=0.f;
    #pragma unroll
    for (int j=0;j<9;++j){
      float p = s[j];
      int rj = pr*9 + j;
      int rmj = rj % 24;
      #pragma unroll
      for (int q4=0;q4<2;++q4){
        int gv = 16 + hf*2 + q4 + rmj; if (gv >= 24) gv -= 24;
        // V granules: hf selects 16..19 or 20..23? No: V spans g=16..23 (8 granules, 128B);
        // half hf covers granules 16+hf*4 .. 19+hf*4
        (void)gv;
      }
      #pragma unroll
      for (int q4=0;q4<4;++q4){
        int g = 16 + hf*4 + q4;
        int gp = g + rmj; if (gp >= 24) gp -= 24;
        uint4 vv = *(const uint4*)(&kvs[rj*96 + gp*4]);
        o[q4*8+0] += p*b2f((unsigned short)(vv.x&0xffffu));
        o[q4*8+1] += p*b2f((unsigned short)(vv.x>>16));
        o[q4*8+2] += p*b2f((unsigned short)(vv.y&0xffffu));
        o[q4*8+3] += p*b2f((unsigned short)(vv.y>>16));
        o[q4*8+4] += p*b2f((unsigned short)(vv.z&0xffffu));
        o[q4*8+5] += p*b2f((unsigned short)(vv.z>>16));
        o[q4*8+6] += p*b2f((unsigned short)(vv.w&0xffffu));
        o[q4*8+7] += p*b2f((unsigned short)(vv.w>>16));
      }
    }
    #pragma unroll
    for (int t8=0;t8<4;++t8){
      u16x8 v;
      #pragma unroll
      for (int e=0;e<8;++e) v[e]=f2b(o[t8*8+e]);
      ((u16x8*)op)[hf*4 + t8] = v;
    }
  }
}

extern "C" void kernel_launch(void* const* d_in, const int* in_sizes, int n_in,
                              void* d_out, int out_size, void* d_ws, size_t ws_size,
                              hipStream_t stream){
  const float* x    = (const float*)d_in[0];
  const float* demo = (const float*)d_in[1];
  const float* Wq   = (const float*)d_in[2];
  const float* Wp   = (const float*)d_in[3];
  const float* bp   = (const float*)d_in[4];
  float* outp = (float*)d_out;

  char* wsb = (char*)d_ws;
  unsigned short* xb   = (unsigned short*)wsb;              // x bf16; reused as attn out
  unsigned short* Wq_t = (unsigned short*)(wsb + 56623104); // [2304][768]
  unsigned short* Wp_t = (unsigned short*)(wsb + 60162048); // [768][768]
  float* cs = (float*)(wsb + 61341696);
  float* sn = cs + SEQ*DH;
  unsigned short* qkv  = (unsigned short*)(wsb + 61346304); // head-major [49152][9][192]

  k_prep <<< PREP_BLKS, 256, 0, stream >>> (x, xb, Wq, Wq_t, Wp, Wp_t, cs, sn);

  {
    int nwg = (MROWS/256)*(NQKV/256);   // 144*9 = 1296, %8==0
    k_gemm8p<0><<< nwg, 512, 0, stream >>>
        (xb, Wq_t, qkv, nullptr, MROWS, NQKV, NQKV/256, nwg);
  }

  k_attn <<< (NPAIR + PPB2 - 1)/PPB2, 192, 0, stream >>> (qkv, demo, cs, sn, xb);

  {
    int nwg = (MROWS/256)*(CDIM/128);   // 144*6 = 864, %8==0
    k_gemm2b<<< nwg, 512, 0, stream >>>
        (xb, Wp_t, outp, bp, MROWS, CDIM, CDIM/128, nwg);
  }
}

// Round 11
// 374.505 us; speedup vs baseline: 1.1365x; 1.1365x over previous
//
#include <hip/hip_runtime.h>
#include <cstdint>
#include <cstddef>

typedef __bf16  bf16x8 __attribute__((ext_vector_type(8)));
typedef float   f32x4  __attribute__((ext_vector_type(4)));
typedef unsigned short u16x8 __attribute__((ext_vector_type(8)));
typedef unsigned short u16x4 __attribute__((ext_vector_type(4)));

#define B_SZ  4096
#define SEQ   9
#define CDIM  768
#define HEADS 12
#define DH    64
#define MROWS (B_SZ*SEQ)      // 36864
#define NQKV  (3*CDIM)        // 2304
#define NPAIR (B_SZ*HEADS)    // 49152
#define PPB   28
#define GK    768             // K for both GEMMs
#define NTK   12              // K-tiles for 256^2 kernel (GK/64)
#define NT2   24              // K-tiles for 256x128 kernel (GK/32)

#define AS1 __attribute__((address_space(1)))
#define AS3 __attribute__((address_space(3)))

__device__ inline float b2f(unsigned short u){
  union{unsigned i; float f;} x; x.i = ((unsigned)u)<<16; return x.f;
}
__device__ inline unsigned short f2b(float f){ // RNE fp32->bf16
  unsigned x = __float_as_uint(f);
  return (unsigned short)((x + 0x7fffu + ((x>>16)&1u)) >> 16);
}

// ======= fused prep: x->bf16, LDS-tiled Wq^T, Wp^T, table — 1 launch =======
#define CONV_BLKS (MROWS*CDIM/1024)          // 27648
#define TCQ_BLKS  ((CDIM/64)*(NQKV/64))      // 432
#define TCP_BLKS  ((CDIM/64)*(CDIM/64))      // 144
#define PREP_BLKS (CONV_BLKS+TCQ_BLKS+TCP_BLKS+1)  // 28225

__device__ inline void tconv_tile(const float* __restrict__ in,
                                  unsigned short* __restrict__ out,
                                  int R, int C, int tr, int tc,
                                  float (*tl)[65], int tid){
  int r0 = tr*64, c0 = tc*64;
  int lr = tid >> 4, lc = (tid & 15)*4;
  #pragma unroll
  for (int p=0;p<4;++p){
    float4 v = *(const float4*)(&in[(size_t)(r0+lr+p*16)*C + c0+lc]);
    tl[lr+p*16][lc]=v.x; tl[lr+p*16][lc+1]=v.y; tl[lr+p*16][lc+2]=v.z; tl[lr+p*16][lc+3]=v.w;
  }
  __syncthreads();
  #pragma unroll
  for (int p=0;p<4;++p){
    int oc = lr+p*16;
    u16x4 o;
    o.x = f2b(tl[lc+0][oc]); o.y = f2b(tl[lc+1][oc]);
    o.z = f2b(tl[lc+2][oc]); o.w = f2b(tl[lc+3][oc]);
    *(u16x4*)(&out[(size_t)(c0+oc)*R + r0 + lc]) = o;
  }
}

__global__ __launch_bounds__(256) void k_prep(const float* __restrict__ x,
                                              unsigned short* __restrict__ xb,
                                              const float* __restrict__ Wq,
                                              unsigned short* __restrict__ Wq_t,
                                              const float* __restrict__ Wp,
                                              unsigned short* __restrict__ Wp_t,
                                              float* __restrict__ cs,
                                              float* __restrict__ sn){
  __shared__ float tl[64][65];
  int blk = blockIdx.x, tid = threadIdx.x;
  if (blk < CONV_BLKS){
    int t = blk*256 + tid;
    float4 v = ((const float4*)x)[t];
    u16x4 o; o.x=f2b(v.x); o.y=f2b(v.y); o.z=f2b(v.z); o.w=f2b(v.w);
    ((u16x4*)xb)[t] = o;
  } else if (blk < CONV_BLKS+TCQ_BLKS){
    int b2 = blk - CONV_BLKS;
    tconv_tile(Wq, Wq_t, CDIM, NQKV, b2/36, b2%36, tl, tid);
  } else if (blk < CONV_BLKS+TCQ_BLKS+TCP_BLKS){
    int b3 = blk - CONV_BLKS - TCQ_BLKS;
    tconv_tile(Wp, Wp_t, CDIM, CDIM, b3/12, b3%12, tl, tid);
  } else {
    for (int t=tid; t<SEQ*DH; t+=256){
      const float blo[9] = {1.f,4.f,8.f,10.f,12.f,30.f,1.f,8.f,1.f};
      const float bhi[9] = {4.f,8.f,10.f,12.f,30.f,45.f,8.f,30.f,45.f};
      int n = t / DH, d = t - n*DH;
      int f = (d < 32) ? (d>>1) : ((d-32)>>1);
      float freq = 3.14159265358979f * (1.0f + (4.0f/15.0f)*(float)f);
      float band = (d < 32) ? blo[n] : bhi[n];
      float ang = band * freq;
      cs[t] = cosf(ang);
      sn[t] = sinf(ang);
    }
  }
}

// ---- shared GEMM phase machinery ----
#define GLOAD(SRC, LDSOFF) \
  __builtin_amdgcn_global_load_lds((const AS1 void*)(SRC), \
      (AS3 void*)(smem + (LDSOFF) + (w<<10)), 16, 0, 0)

#define PHASE_MID  do{ __builtin_amdgcn_s_barrier(); \
  asm volatile("s_waitcnt lgkmcnt(0)" ::: "memory"); \
  __builtin_amdgcn_sched_barrier(0); \
  __builtin_amdgcn_s_setprio(1); }while(0)
#define PHASE_END  do{ __builtin_amdgcn_s_setprio(0); \
  __builtin_amdgcn_s_barrier(); }while(0)

// ====== GEMM1: 256x256, BK=64, 4 balanced phases per K-tile (R4 best) ======
// Epilogue now applies dRoFE rope to q,k columns via __shfl_xor pairing.
#define RD_A(SLOT, H) do{ _Pragma("unroll") \
  for (int m=0;m<4;++m) aQ[m] = *(const bf16x8*)((SLOT) + aRd + ((H)*4+m)*1024); }while(0)
#define RD_B(SLOT) do{ _Pragma("unroll") \
  for (int n=0;n<4;++n) bR[n] = *(const bf16x8*)((SLOT) + bRd + n*1024); }while(0)
#define MFMA_Q(H) do{ _Pragma("unroll") \
  for (int m=0;m<4;++m){ _Pragma("unroll") \
    for (int n=0;n<4;++n) \
      acc[(H)*4+m][n] = __builtin_amdgcn_mfma_f32_16x16x32_bf16(aQ[m], bR[n], acc[(H)*4+m][n], 0,0,0); } }while(0)

#define TILE_BODY(T, DB) do{ \
  const char* aS0 = smem + (DB)*16384; \
  const char* aS1 = smem + ((DB)+1)*16384; \
  const char* bS0 = smem + 65536 + (DB)*16384; \
  const char* bS1 = smem + 65536 + ((DB)+1)*16384; \
  int u1=(T)+1; if(u1>NTK-1)u1=NTK-1; int u2=(T)+2; if(u2>NTK-1)u2=NTK-1; \
  size_t o1=(size_t)u1*64+32, o2a=(size_t)u2*64, o2b=o2a+32; \
  /* P1: A mi0-3 k0, B k0; stage B1(t+1) */ \
  RD_A(aS0,0); RD_B(bS0); \
  GLOAD(bSrc0+o1, 65536 + (3-(DB))*16384); \
  GLOAD(bSrc1+o1, 65536 + (3-(DB))*16384 + 8192); \
  PHASE_MID; MFMA_Q(0); PHASE_END; \
  /* P2: A mi4-7 k0; stage A0(t+2) */ \
  RD_A(aS0,1); \
  GLOAD(aSrc0+o2a, (DB)*16384); \
  GLOAD(aSrc1+o2a, (DB)*16384 + 8192); \
  PHASE_MID; MFMA_Q(1); PHASE_END; \
  /* P3: A mi0-3 k1, B k1; stage B0(t+2) */ \
  RD_A(aS1,0); RD_B(bS1); \
  GLOAD(bSrc0+o2a, 65536 + (DB)*16384); \
  GLOAD(bSrc1+o2a, 65536 + (DB)*16384 + 8192); \
  PHASE_MID; MFMA_Q(0); PHASE_END; \
  /* P4: A mi4-7 k1; stage A1(t+2); vmcnt(6) */ \
  RD_A(aS1,1); \
  GLOAD(aSrc0+o2b, ((DB)+1)*16384); \
  GLOAD(aSrc1+o2b, ((DB)+1)*16384 + 8192); \
  PHASE_MID; MFMA_Q(1); \
  __builtin_amdgcn_s_setprio(0); \
  asm volatile("s_waitcnt vmcnt(6)" ::: "memory"); \
  __builtin_amdgcn_s_barrier(); }while(0)

template<int WRITE_F32>
__global__ __launch_bounds__(512, 2) void k_gemm8p(const unsigned short* __restrict__ A,
                                                   const unsigned short* __restrict__ Bt,
                                                   void* __restrict__ Cout,
                                                   const float* __restrict__ bias,
                                                   const float* __restrict__ demo,
                                                   const float* __restrict__ cs,
                                                   const float* __restrict__ sn,
                                                   int M, int N, int NTN, int NWG){
  __shared__ char smem[131072];   // A ring 4x16KB | B ring 4x16KB
  int wg = blockIdx.x;
  int cpx = NWG >> 3;
  int swz = (wg & 7)*cpx + (wg >> 3);          // bijective (NWG%8==0)
  int bm = swz / NTN, bn = swz - bm*NTN;
  int m0 = bm << 8, n0 = bn << 8;

  int tid = threadIdx.x;
  int w = tid >> 6, lane = tid & 63;
  int r = lane & 15, g4 = lane >> 4;
  int wr = w >> 2, wc = w & 3;

  // st_16x32 read-side: 16B-granule g4 ^= 2*row_bit3 (verified 0-conflict)
  int seg = g4 ^ (((r >> 3) & 1) << 1);
  int aRd = (wr*128 + r)*64 + seg*16;
  int bRd = (wc*64  + r)*64 + seg*16;

  // staging side (pre-swizzled global source; linear LDS dest)
  int srow = tid >> 2;
  int gsw  = (tid & 3) ^ (((tid >> 5) & 1) << 1);
  const unsigned short* aSrc0 = A  + (size_t)(m0 + srow)*GK + gsw*8;
  const unsigned short* aSrc1 = aSrc0 + (size_t)128*GK;
  const unsigned short* bSrc0 = Bt + (size_t)(n0 + srow)*GK + gsw*8;
  const unsigned short* bSrc1 = bSrc0 + (size_t)128*GK;

  const f32x4 fz = {0.f,0.f,0.f,0.f};
  f32x4 acc[8][4];
  #pragma unroll
  for (int mi=0;mi<8;++mi)
    #pragma unroll
    for (int ni=0;ni<4;++ni) acc[mi][ni] = fz;
  bf16x8 aQ[4], bR[4];

  // ---- prologue: 7 half-tiles ----
  GLOAD(aSrc0+ 0,     0); GLOAD(aSrc1+ 0,  8192);
  GLOAD(bSrc0+ 0, 65536); GLOAD(bSrc1+ 0, 65536+ 8192);
  GLOAD(aSrc0+32, 16384); GLOAD(aSrc1+32, 16384+8192);
  GLOAD(bSrc0+32, 65536+16384); GLOAD(bSrc1+32, 65536+16384+8192);
  GLOAD(aSrc0+64, 32768); GLOAD(aSrc1+64, 32768+8192);
  GLOAD(bSrc0+64, 65536+32768); GLOAD(bSrc1+64, 65536+32768+8192);
  GLOAD(aSrc0+96, 49152); GLOAD(aSrc1+96, 49152+8192);
  asm volatile("s_waitcnt vmcnt(6)" ::: "memory");
  __builtin_amdgcn_s_barrier();

  #pragma unroll 1
  for (int tt=0; tt<NTK; tt+=2){
    TILE_BODY(tt,   0);
    TILE_BODY(tt+1, 2);
  }
  asm volatile("s_waitcnt vmcnt(0)" ::: "memory");

  // ---- epilogue: C/D layout col=lane&15, row=(lane>>4)*4+q ----
  if (WRITE_F32){
    #pragma unroll
    for (int mi=0;mi<8;++mi){
      #pragma unroll
      for (int ni=0;ni<4;++ni){
        int col = n0 + wc*64 + ni*16 + r;
        float bb = bias ? bias[col] : 0.f;
        #pragma unroll
        for (int q=0;q<4;++q){
          int row = m0 + wr*128 + mi*16 + g4*4 + q;
          ((float*)Cout)[(size_t)row*N + col] = acc[mi][ni][q] + bb;
        }
      }
    }
  } else {
    // head-major qkv + fused dRoFE rope on q,k columns.
    #pragma unroll
    for (int mi=0;mi<8;++mi){
      #pragma unroll
      for (int q=0;q<4;++q){
        int row = m0 + wr*128 + mi*16 + g4*4 + q;
        int bb = row / 9;
        int ii = row - bb*9;
        float age = demo[2*bb], gen = demo[2*bb+1];
        size_t rb = (size_t)bb*HEADS;
        #pragma unroll
        for (int ni=0;ni<4;++ni){
          int col = n0 + wc*64 + ni*16 + r;
          int which = (col >= 1536) ? 2 : (col >= 768 ? 1 : 0);
          int rem = col - which*768;
          int h = rem >> 6, d = rem & 63;
          float val = acc[mi][ni][q];
          float pv = __shfl_xor(val, 1);      // partner element (d^1), same row
          if (which < 2){                      // wave-uniform branch
            float c = cs[ii*64+d], sv = sn[ii*64+d];
            float ev = age*val*c - gen*pv*sv;  // even d
            float ov = age*val*c + gen*pv*sv;  // odd d
            val = (d & 1) ? ov : ev;
          }
          size_t idx = ((rb + h)*9 + ii)*192 + which*64 + d;
          ((unsigned short*)Cout)[idx] = f2b(val);
        }
      }
    }
  }
}

// ============ GEMM2: 256x128, BK=32, 3-slot ring, 2 blocks/CU ============
#define TILE2(T, SL, SP) do{ \
  const char* aS = smem + (SL)*16384; \
  const char* bS = smem + 49152 + (SL)*8192; \
  int u2=(T)+2; if(u2>NT2-1)u2=NT2-1; size_t o2=(size_t)u2*32; \
  _Pragma("unroll") for (int m=0;m<4;++m) aQ[m] = *(const bf16x8*)(aS + aRd + m*1024); \
  _Pragma("unroll") for (int n=0;n<4;++n) bR[n] = *(const bf16x8*)(bS + bRd + n*1024); \
  GLOAD(aSrc0+o2, (SP)*16384); \
  GLOAD(aSrc1+o2, (SP)*16384 + 8192); \
  GLOAD(bSrc +o2, 49152 + (SP)*8192); \
  PHASE_MID; \
  _Pragma("unroll") for (int m=0;m<4;++m){ _Pragma("unroll") for (int n=0;n<4;++n) \
    acc[m][n] = __builtin_amdgcn_mfma_f32_16x16x32_bf16(aQ[m], bR[n], acc[m][n], 0,0,0); } \
  __builtin_amdgcn_s_setprio(0); \
  asm volatile("s_waitcnt vmcnt(3)" ::: "memory"); \
  __builtin_amdgcn_s_barrier(); }while(0)

__global__ __launch_bounds__(512, 4) void k_gemm2b(const unsigned short* __restrict__ A,
                                                   const unsigned short* __restrict__ Bt,
                                                   float* __restrict__ C,
                                                   const float* __restrict__ bias,
                                                   int M, int N, int NTN, int NWG){
  __shared__ char smem[73728];   // A 3x16KB | B 3x8KB
  int wg = blockIdx.x;
  int cpx = NWG >> 3;
  int swz = (wg & 7)*cpx + (wg >> 3);
  int bm = swz / NTN, bn = swz - bm*NTN;
  int m0 = bm << 8, n0 = bn << 7;

  int tid = threadIdx.x;
  int w = tid >> 6, lane = tid & 63;
  int r = lane & 15, g4 = lane >> 4;
  int wr = w >> 1, wc = w & 1;

  int seg = g4 ^ (((r >> 3) & 1) << 1);
  int aRd = (wr*64 + r)*64 + seg*16;
  int bRd = (wc*64 + r)*64 + seg*16;

  int srow = tid >> 2;
  int gsw  = (tid & 3) ^ (((tid >> 5) & 1) << 1);
  const unsigned short* aSrc0 = A  + (size_t)(m0 + srow)*GK + gsw*8;
  const unsigned short* aSrc1 = aSrc0 + (size_t)128*GK;
  const unsigned short* bSrc  = Bt + (size_t)(n0 + srow)*GK + gsw*8;

  const f32x4 fz = {0.f,0.f,0.f,0.f};
  f32x4 acc[4][4];
  #pragma unroll
  for (int m=0;m<4;++m)
    #pragma unroll
    for (int n=0;n<4;++n) acc[m][n] = fz;
  bf16x8 aQ[4], bR[4];

  GLOAD(aSrc0+ 0, 0);     GLOAD(aSrc1+ 0, 8192);       GLOAD(bSrc+ 0, 49152);
  GLOAD(aSrc0+32, 16384); GLOAD(aSrc1+32, 16384+8192); GLOAD(bSrc+32, 49152+8192);
  asm volatile("s_waitcnt vmcnt(3)" ::: "memory");
  __builtin_amdgcn_s_barrier();

  #pragma unroll 1
  for (int tt=0; tt<NT2; tt+=3){
    TILE2(tt,   0, 2);
    TILE2(tt+1, 1, 0);
    TILE2(tt+2, 2, 1);
  }
  asm volatile("s_waitcnt vmcnt(0)" ::: "memory");

  #pragma unroll
  for (int mi=0;mi<4;++mi){
    #pragma unroll
    for (int ni=0;ni<4;++ni){
      int col = n0 + wc*64 + ni*16 + r;
      float bb = bias ? bias[col] : 0.f;
      #pragma unroll
      for (int q=0;q<4;++q){
        int row = m0 + wr*64 + mi*16 + g4*4 + q;
        C[(size_t)row*N + col] = acc[mi][ni][q] + bb;
      }
    }
  }
}

// ====== dRoFE attention v6: rope pre-applied in GEMM1 -> pure copy/stage ===
// qkv rows already hold roped q,k (and raw v). K,V staged in LDS (v3 layout,
// measured good); Q loaded straight to regs. No cs/sn, no rope math here.
__global__ __launch_bounds__(256) void k_attn(const unsigned short* __restrict__ qkv,
                                              unsigned short* __restrict__ out){
  __shared__ __align__(16) unsigned int kv[PPB][SEQ][68];
  int tid = threadIdx.x;
  int pr = tid / 9, i = tid - pr*9;
  int pair = blockIdx.x*PPB + pr;
  bool act = (pr < PPB) && (pair < NPAIR);
  int b = 0, h = 0;
  const unsigned short* base = qkv;
  if (act){
    b = pair / HEADS; h = pair - b*HEADS;
    base = qkv + (size_t)pair*(SEQ*192);
  }

  float qr[64];
  if (act){
    const u16x8* qp = (const u16x8*)(base + (size_t)i*192);
    const uint4* kp = (const uint4*)(base + (size_t)i*192 + 64);
    const uint4* vp = (const uint4*)(base + (size_t)i*192 + 128);
    #pragma unroll
    for (int t8=0;t8<8;++t8){
      u16x8 qv = qp[t8];
      #pragma unroll
      for (int e=0;e<8;++e) qr[t8*8+e] = b2f(qv[e]);
      *(uint4*)(&kv[pr][i][t8*4])    = kp[t8];   // roped K (copy)
      *(uint4*)(&kv[pr][i][32+t8*4]) = vp[t8];   // raw V (copy)
    }
  }
  __syncthreads();   // K,V staged

  if (!act) return;

  float s[9]; float mx = -1e30f;
  #pragma unroll
  for (int j=0;j<9;++j){
    const uint4* kr = (const uint4*)(&kv[pr][j][0]);
    float acc = 0.f;
    #pragma unroll
    for (int q8=0;q8<8;++q8){
      uint4 kk = kr[q8];
      acc += qr[q8*8+0]*b2f((unsigned short)(kk.x&0xffffu)) + qr[q8*8+1]*b2f((unsigned short)(kk.x>>16));
      acc += qr[q8*8+2]*b2f((unsigned short)(kk.y&0xffffu)) + qr[q8*8+3]*b2f((unsigned short)(kk.y>>16));
      acc += qr[q8*8+4]*b2f((unsigned short)(kk.z&0xffffu)) + qr[q8*8+5]*b2f((unsigned short)(kk.z>>16));
      acc += qr[q8*8+6]*b2f((unsigned short)(kk.w&0xffffu)) + qr[q8*8+7]*b2f((unsigned short)(kk.w>>16));
    }
    s[j] = acc * 0.125f;
    mx = fmaxf(mx, s[j]);
  }
  float den = 0.f;
  #pragma unroll
  for (int j=0;j<9;++j){ s[j] = __expf(s[j]-mx); den += s[j]; }
  float inv = 1.f/den;
  #pragma unroll
  for (int j=0;j<9;++j) s[j] *= inv;

  // PV in two 32-dim halves (o[32] keeps VGPR < 128)
  unsigned short* op = out + (size_t)(b*SEQ+i)*CDIM + h*DH;
  #pragma unroll
  for (int hf=0; hf<2; ++hf){
    float o[32];
    #pragma unroll
    for (int d=0;d<32;++d) o[d]=0.f;
    #pragma unroll
    for (int j=0;j<9;++j){
      float p = s[j];
      const uint4* vr = (const uint4*)(&kv[pr][j][32 + hf*16]);
      #pragma unroll
      for (int q4=0;q4<4;++q4){
        uint4 vv = vr[q4];
        o[q4*8+0] += p*b2f((unsigned short)(vv.x&0xffffu));
        o[q4*8+1] += p*b2f((unsigned short)(vv.x>>16));
        o[q4*8+2] += p*b2f((unsigned short)(vv.y&0xffffu));
        o[q4*8+3] += p*b2f((unsigned short)(vv.y>>16));
        o[q4*8+4] += p*b2f((unsigned short)(vv.z&0xffffu));
        o[q4*8+5] += p*b2f((unsigned short)(vv.z>>16));
        o[q4*8+6] += p*b2f((unsigned short)(vv.w&0xffffu));
        o[q4*8+7] += p*b2f((unsigned short)(vv.w>>16));
      }
    }
    #pragma unroll
    for (int t8=0;t8<4;++t8){
      u16x8 v;
      #pragma unroll
      for (int e=0;e<8;++e) v[e]=f2b(o[t8*8+e]);
      ((u16x8*)op)[hf*4 + t8] = v;
    }
  }
}

extern "C" void kernel_launch(void* const* d_in, const int* in_sizes, int n_in,
                              void* d_out, int out_size, void* d_ws, size_t ws_size,
                              hipStream_t stream){
  const float* x    = (const float*)d_in[0];
  const float* demo = (const float*)d_in[1];
  const float* Wq   = (const float*)d_in[2];
  const float* Wp   = (const float*)d_in[3];
  const float* bp   = (const float*)d_in[4];
  float* outp = (float*)d_out;

  char* wsb = (char*)d_ws;
  unsigned short* xb   = (unsigned short*)wsb;              // x bf16; reused as attn out
  unsigned short* Wq_t = (unsigned short*)(wsb + 56623104); // [2304][768]
  unsigned short* Wp_t = (unsigned short*)(wsb + 60162048); // [768][768]
  float* cs = (float*)(wsb + 61341696);
  float* sn = cs + SEQ*DH;
  unsigned short* qkv  = (unsigned short*)(wsb + 61346304); // head-major [49152][9][192]

  k_prep <<< PREP_BLKS, 256, 0, stream >>> (x, xb, Wq, Wq_t, Wp, Wp_t, cs, sn);

  {
    int nwg = (MROWS/256)*(NQKV/256);   // 144*9 = 1296, %8==0
    k_gemm8p<0><<< nwg, 512, 0, stream >>>
        (xb, Wq_t, qkv, nullptr, demo, cs, sn, MROWS, NQKV, NQKV/256, nwg);
  }

  k_attn <<< (NPAIR + PPB - 1)/PPB, 256, 0, stream >>> (qkv, xb);

  {
    int nwg = (MROWS/256)*(CDIM/128);   // 144*6 = 864, %8==0
    k_gemm2b<<< nwg, 512, 0, stream >>>
        (xb, Wp_t, outp, bp, MROWS, CDIM, CDIM/128, nwg);
  }
}

// Round 12
// 331.094 us; speedup vs baseline: 1.2855x; 1.1311x over previous
//
#include <hip/hip_runtime.h>
#include <cstdint>
#include <cstddef>

typedef __bf16  bf16x8 __attribute__((ext_vector_type(8)));
typedef float   f32x4  __attribute__((ext_vector_type(4)));
typedef unsigned short u16x8 __attribute__((ext_vector_type(8)));
typedef unsigned short u16x4 __attribute__((ext_vector_type(4)));

#define B_SZ  4096
#define SEQ   9
#define CDIM  768
#define HEADS 12
#define DH    64
#define MROWS (B_SZ*SEQ)      // 36864
#define NQKV  (3*CDIM)        // 2304
#define NPAIR (B_SZ*HEADS)    // 49152
#define PPB   28
#define GK    768             // K for both GEMMs
#define NTK   12              // K-tiles for 256^2 kernel (GK/64)
#define NT2   24              // K-tiles for 256x128 kernel (GK/32)

#define AS1 __attribute__((address_space(1)))
#define AS3 __attribute__((address_space(3)))

__device__ inline float b2f(unsigned short u){
  union{unsigned i; float f;} x; x.i = ((unsigned)u)<<16; return x.f;
}
__device__ inline unsigned short f2b(float f){ // RNE fp32->bf16
  unsigned x = __float_as_uint(f);
  return (unsigned short)((x + 0x7fffu + ((x>>16)&1u)) >> 16);
}

// ======= fused prep: x->bf16, LDS-tiled Wq^T, Wp^T, table — 1 launch =======
#define CONV_BLKS (MROWS*CDIM/1024)          // 27648
#define TCQ_BLKS  ((CDIM/64)*(NQKV/64))      // 432
#define TCP_BLKS  ((CDIM/64)*(CDIM/64))      // 144
#define PREP_BLKS (CONV_BLKS+TCQ_BLKS+TCP_BLKS+1)  // 28225

__device__ inline void tconv_tile(const float* __restrict__ in,
                                  unsigned short* __restrict__ out,
                                  int R, int C, int tr, int tc,
                                  float (*tl)[65], int tid){
  int r0 = tr*64, c0 = tc*64;
  int lr = tid >> 4, lc = (tid & 15)*4;
  #pragma unroll
  for (int p=0;p<4;++p){
    float4 v = *(const float4*)(&in[(size_t)(r0+lr+p*16)*C + c0+lc]);
    tl[lr+p*16][lc]=v.x; tl[lr+p*16][lc+1]=v.y; tl[lr+p*16][lc+2]=v.z; tl[lr+p*16][lc+3]=v.w;
  }
  __syncthreads();
  #pragma unroll
  for (int p=0;p<4;++p){
    int oc = lr+p*16;
    u16x4 o;
    o.x = f2b(tl[lc+0][oc]); o.y = f2b(tl[lc+1][oc]);
    o.z = f2b(tl[lc+2][oc]); o.w = f2b(tl[lc+3][oc]);
    *(u16x4*)(&out[(size_t)(c0+oc)*R + r0 + lc]) = o;
  }
}

__global__ __launch_bounds__(256) void k_prep(const float* __restrict__ x,
                                              unsigned short* __restrict__ xb,
                                              const float* __restrict__ Wq,
                                              unsigned short* __restrict__ Wq_t,
                                              const float* __restrict__ Wp,
                                              unsigned short* __restrict__ Wp_t,
                                              float* __restrict__ cs,
                                              float* __restrict__ sn){
  __shared__ float tl[64][65];
  int blk = blockIdx.x, tid = threadIdx.x;
  if (blk < CONV_BLKS){
    int t = blk*256 + tid;
    float4 v = ((const float4*)x)[t];
    u16x4 o; o.x=f2b(v.x); o.y=f2b(v.y); o.z=f2b(v.z); o.w=f2b(v.w);
    ((u16x4*)xb)[t] = o;
  } else if (blk < CONV_BLKS+TCQ_BLKS){
    int b2 = blk - CONV_BLKS;
    tconv_tile(Wq, Wq_t, CDIM, NQKV, b2/36, b2%36, tl, tid);
  } else if (blk < CONV_BLKS+TCQ_BLKS+TCP_BLKS){
    int b3 = blk - CONV_BLKS - TCQ_BLKS;
    tconv_tile(Wp, Wp_t, CDIM, CDIM, b3/12, b3%12, tl, tid);
  } else {
    for (int t=tid; t<SEQ*DH; t+=256){
      const float blo[9] = {1.f,4.f,8.f,10.f,12.f,30.f,1.f,8.f,1.f};
      const float bhi[9] = {4.f,8.f,10.f,12.f,30.f,45.f,8.f,30.f,45.f};
      int n = t / DH, d = t - n*DH;
      int f = (d < 32) ? (d>>1) : ((d-32)>>1);
      float freq = 3.14159265358979f * (1.0f + (4.0f/15.0f)*(float)f);
      float band = (d < 32) ? blo[n] : bhi[n];
      float ang = band * freq;
      cs[t] = cosf(ang);
      sn[t] = sinf(ang);
    }
  }
}

// ---- shared GEMM phase machinery ----
#define GLOAD(SRC, LDSOFF) \
  __builtin_amdgcn_global_load_lds((const AS1 void*)(SRC), \
      (AS3 void*)(smem + (LDSOFF) + (w<<10)), 16, 0, 0)

#define PHASE_MID  do{ __builtin_amdgcn_s_barrier(); \
  asm volatile("s_waitcnt lgkmcnt(0)" ::: "memory"); \
  __builtin_amdgcn_sched_barrier(0); \
  __builtin_amdgcn_s_setprio(1); }while(0)
#define PHASE_END  do{ __builtin_amdgcn_s_setprio(0); \
  __builtin_amdgcn_s_barrier(); }while(0)

// ====== GEMM1: 256x256, BK=64, 4 balanced phases per K-tile (R4 best) ======
// Epilogue applies dRoFE rope via __shfl_xor, with cs/sn/demo staged in LDS.
#define RD_A(SLOT, H) do{ _Pragma("unroll") \
  for (int m=0;m<4;++m) aQ[m] = *(const bf16x8*)((SLOT) + aRd + ((H)*4+m)*1024); }while(0)
#define RD_B(SLOT) do{ _Pragma("unroll") \
  for (int n=0;n<4;++n) bR[n] = *(const bf16x8*)((SLOT) + bRd + n*1024); }while(0)
#define MFMA_Q(H) do{ _Pragma("unroll") \
  for (int m=0;m<4;++m){ _Pragma("unroll") \
    for (int n=0;n<4;++n) \
      acc[(H)*4+m][n] = __builtin_amdgcn_mfma_f32_16x16x32_bf16(aQ[m], bR[n], acc[(H)*4+m][n], 0,0,0); } }while(0)

#define TILE_BODY(T, DB) do{ \
  const char* aS0 = smem + (DB)*16384; \
  const char* aS1 = smem + ((DB)+1)*16384; \
  const char* bS0 = smem + 65536 + (DB)*16384; \
  const char* bS1 = smem + 65536 + ((DB)+1)*16384; \
  int u1=(T)+1; if(u1>NTK-1)u1=NTK-1; int u2=(T)+2; if(u2>NTK-1)u2=NTK-1; \
  size_t o1=(size_t)u1*64+32, o2a=(size_t)u2*64, o2b=o2a+32; \
  /* P1: A mi0-3 k0, B k0; stage B1(t+1) */ \
  RD_A(aS0,0); RD_B(bS0); \
  GLOAD(bSrc0+o1, 65536 + (3-(DB))*16384); \
  GLOAD(bSrc1+o1, 65536 + (3-(DB))*16384 + 8192); \
  PHASE_MID; MFMA_Q(0); PHASE_END; \
  /* P2: A mi4-7 k0; stage A0(t+2) */ \
  RD_A(aS0,1); \
  GLOAD(aSrc0+o2a, (DB)*16384); \
  GLOAD(aSrc1+o2a, (DB)*16384 + 8192); \
  PHASE_MID; MFMA_Q(1); PHASE_END; \
  /* P3: A mi0-3 k1, B k1; stage B0(t+2) */ \
  RD_A(aS1,0); RD_B(bS1); \
  GLOAD(bSrc0+o2a, 65536 + (DB)*16384); \
  GLOAD(bSrc1+o2a, 65536 + (DB)*16384 + 8192); \
  PHASE_MID; MFMA_Q(0); PHASE_END; \
  /* P4: A mi4-7 k1; stage A1(t+2); vmcnt(6) */ \
  RD_A(aS1,1); \
  GLOAD(aSrc0+o2b, ((DB)+1)*16384); \
  GLOAD(aSrc1+o2b, ((DB)+1)*16384 + 8192); \
  PHASE_MID; MFMA_Q(1); \
  __builtin_amdgcn_s_setprio(0); \
  asm volatile("s_waitcnt vmcnt(6)" ::: "memory"); \
  __builtin_amdgcn_s_barrier(); }while(0)

template<int WRITE_F32>
__global__ __launch_bounds__(512, 2) void k_gemm8p(const unsigned short* __restrict__ A,
                                                   const unsigned short* __restrict__ Bt,
                                                   void* __restrict__ Cout,
                                                   const float* __restrict__ bias,
                                                   const float* __restrict__ demo,
                                                   const float* __restrict__ cs,
                                                   const float* __restrict__ sn,
                                                   int M, int N, int NTN, int NWG){
  __shared__ char smem[131072];   // A ring 4x16KB | B ring 4x16KB
  int wg = blockIdx.x;
  int cpx = NWG >> 3;
  int swz = (wg & 7)*cpx + (wg >> 3);          // bijective (NWG%8==0)
  int bm = swz / NTN, bn = swz - bm*NTN;
  int m0 = bm << 8, n0 = bn << 8;

  int tid = threadIdx.x;
  int w = tid >> 6, lane = tid & 63;
  int r = lane & 15, g4 = lane >> 4;
  int wr = w >> 2, wc = w & 3;

  // st_16x32 read-side: 16B-granule g4 ^= 2*row_bit3 (verified 0-conflict)
  int seg = g4 ^ (((r >> 3) & 1) << 1);
  int aRd = (wr*128 + r)*64 + seg*16;
  int bRd = (wc*64  + r)*64 + seg*16;

  // staging side (pre-swizzled global source; linear LDS dest)
  int srow = tid >> 2;
  int gsw  = (tid & 3) ^ (((tid >> 5) & 1) << 1);
  const unsigned short* aSrc0 = A  + (size_t)(m0 + srow)*GK + gsw*8;
  const unsigned short* aSrc1 = aSrc0 + (size_t)128*GK;
  const unsigned short* bSrc0 = Bt + (size_t)(n0 + srow)*GK + gsw*8;
  const unsigned short* bSrc1 = bSrc0 + (size_t)128*GK;

  const f32x4 fz = {0.f,0.f,0.f,0.f};
  f32x4 acc[8][4];
  #pragma unroll
  for (int mi=0;mi<8;++mi)
    #pragma unroll
    for (int ni=0;ni<4;++ni) acc[mi][ni] = fz;
  bf16x8 aQ[4], bR[4];

  // ---- prologue: 7 half-tiles ----
  GLOAD(aSrc0+ 0,     0); GLOAD(aSrc1+ 0,  8192);
  GLOAD(bSrc0+ 0, 65536); GLOAD(bSrc1+ 0, 65536+ 8192);
  GLOAD(aSrc0+32, 16384); GLOAD(aSrc1+32, 16384+8192);
  GLOAD(bSrc0+32, 65536+16384); GLOAD(bSrc1+32, 65536+16384+8192);
  GLOAD(aSrc0+64, 32768); GLOAD(aSrc1+64, 32768+8192);
  GLOAD(bSrc0+64, 65536+32768); GLOAD(bSrc1+64, 65536+32768+8192);
  GLOAD(aSrc0+96, 49152); GLOAD(aSrc1+96, 49152+8192);
  asm volatile("s_waitcnt vmcnt(6)" ::: "memory");
  __builtin_amdgcn_s_barrier();

  #pragma unroll 1
  for (int tt=0; tt<NTK; tt+=2){
    TILE_BODY(tt,   0);
    TILE_BODY(tt+1, 2);
  }
  asm volatile("s_waitcnt vmcnt(0)" ::: "memory");

  // ---- epilogue: C/D layout col=lane&15, row=(lane>>4)*4+q ----
  if (WRITE_F32){
    #pragma unroll
    for (int mi=0;mi<8;++mi){
      #pragma unroll
      for (int ni=0;ni<4;++ni){
        int col = n0 + wc*64 + ni*16 + r;
        float bb = bias ? bias[col] : 0.f;
        #pragma unroll
        for (int q=0;q<4;++q){
          int row = m0 + wr*128 + mi*16 + g4*4 + q;
          ((float*)Cout)[(size_t)row*N + col] = acc[mi][ni][q] + bb;
        }
      }
    }
  } else {
    // K-loop LDS is dead; stage rope tables there (fixes R11's 85M scattered
    // global loads: cs/sn 1152 f32 + block's demo pairs -> LDS).
    float* scs = (float*)smem;             // [576]
    float* ssn = scs + 576;                // [576]
    float* sdm = ssn + 576;                // [64] demo pairs for bb0..bb0+31
    int bb0 = m0 / 9;
    __builtin_amdgcn_s_barrier();          // all waves done reading K-loop LDS
    for (int t = tid; t < 1152; t += 512){
      if (t < 576) scs[t] = cs[t];
      else         ssn[t-576] = sn[t-576];
    }
    for (int t = tid; t < 64; t += 512){
      int gi = 2*bb0 + t;
      sdm[t] = (gi < 2*B_SZ) ? demo[gi] : 0.f;
    }
    __syncthreads();

    #pragma unroll
    for (int mi=0;mi<8;++mi){
      #pragma unroll
      for (int q=0;q<4;++q){
        int row = m0 + wr*128 + mi*16 + g4*4 + q;
        int bb = row / 9;
        int ii = row - bb*9;
        float age = sdm[2*(bb-bb0)], gen = sdm[2*(bb-bb0)+1];
        size_t rb = (size_t)bb*HEADS;
        #pragma unroll
        for (int ni=0;ni<4;++ni){
          int col = n0 + wc*64 + ni*16 + r;
          int which = (col >= 1536) ? 2 : (col >= 768 ? 1 : 0);
          int rem = col - which*768;
          int h = rem >> 6, d = rem & 63;
          float val = acc[mi][ni][q];
          float pv = __shfl_xor(val, 1);      // partner element (d^1), same row
          if (which < 2){                      // wave-uniform branch
            float c = scs[ii*64+d], sv = ssn[ii*64+d];
            float ev = age*val*c - gen*pv*sv;  // even d
            float ov = age*val*c + gen*pv*sv;  // odd d
            val = (d & 1) ? ov : ev;
          }
          size_t idx = ((rb + h)*9 + ii)*192 + which*64 + d;
          ((unsigned short*)Cout)[idx] = f2b(val);
        }
      }
    }
  }
}

// ============ GEMM2: 256x128, BK=32, 3-slot ring, 2 blocks/CU ============
#define TILE2(T, SL, SP) do{ \
  const char* aS = smem + (SL)*16384; \
  const char* bS = smem + 49152 + (SL)*8192; \
  int u2=(T)+2; if(u2>NT2-1)u2=NT2-1; size_t o2=(size_t)u2*32; \
  _Pragma("unroll") for (int m=0;m<4;++m) aQ[m] = *(const bf16x8*)(aS + aRd + m*1024); \
  _Pragma("unroll") for (int n=0;n<4;++n) bR[n] = *(const bf16x8*)(bS + bRd + n*1024); \
  GLOAD(aSrc0+o2, (SP)*16384); \
  GLOAD(aSrc1+o2, (SP)*16384 + 8192); \
  GLOAD(bSrc +o2, 49152 + (SP)*8192); \
  PHASE_MID; \
  _Pragma("unroll") for (int m=0;m<4;++m){ _Pragma("unroll") for (int n=0;n<4;++n) \
    acc[m][n] = __builtin_amdgcn_mfma_f32_16x16x32_bf16(aQ[m], bR[n], acc[m][n], 0,0,0); } \
  __builtin_amdgcn_s_setprio(0); \
  asm volatile("s_waitcnt vmcnt(3)" ::: "memory"); \
  __builtin_amdgcn_s_barrier(); }while(0)

__global__ __launch_bounds__(512, 4) void k_gemm2b(const unsigned short* __restrict__ A,
                                                   const unsigned short* __restrict__ Bt,
                                                   float* __restrict__ C,
                                                   const float* __restrict__ bias,
                                                   int M, int N, int NTN, int NWG){
  __shared__ char smem[73728];   // A 3x16KB | B 3x8KB
  int wg = blockIdx.x;
  int cpx = NWG >> 3;
  int swz = (wg & 7)*cpx + (wg >> 3);
  int bm = swz / NTN, bn = swz - bm*NTN;
  int m0 = bm << 8, n0 = bn << 7;

  int tid = threadIdx.x;
  int w = tid >> 6, lane = tid & 63;
  int r = lane & 15, g4 = lane >> 4;
  int wr = w >> 1, wc = w & 1;

  int seg = g4 ^ (((r >> 3) & 1) << 1);
  int aRd = (wr*64 + r)*64 + seg*16;
  int bRd = (wc*64 + r)*64 + seg*16;

  int srow = tid >> 2;
  int gsw  = (tid & 3) ^ (((tid >> 5) & 1) << 1);
  const unsigned short* aSrc0 = A  + (size_t)(m0 + srow)*GK + gsw*8;
  const unsigned short* aSrc1 = aSrc0 + (size_t)128*GK;
  const unsigned short* bSrc  = Bt + (size_t)(n0 + srow)*GK + gsw*8;

  const f32x4 fz = {0.f,0.f,0.f,0.f};
  f32x4 acc[4][4];
  #pragma unroll
  for (int m=0;m<4;++m)
    #pragma unroll
    for (int n=0;n<4;++n) acc[m][n] = fz;
  bf16x8 aQ[4], bR[4];

  GLOAD(aSrc0+ 0, 0);     GLOAD(aSrc1+ 0, 8192);       GLOAD(bSrc+ 0, 49152);
  GLOAD(aSrc0+32, 16384); GLOAD(aSrc1+32, 16384+8192); GLOAD(bSrc+32, 49152+8192);
  asm volatile("s_waitcnt vmcnt(3)" ::: "memory");
  __builtin_amdgcn_s_barrier();

  #pragma unroll 1
  for (int tt=0; tt<NT2; tt+=3){
    TILE2(tt,   0, 2);
    TILE2(tt+1, 1, 0);
    TILE2(tt+2, 2, 1);
  }
  asm volatile("s_waitcnt vmcnt(0)" ::: "memory");

  #pragma unroll
  for (int mi=0;mi<4;++mi){
    #pragma unroll
    for (int ni=0;ni<4;++ni){
      int col = n0 + wc*64 + ni*16 + r;
      float bb = bias ? bias[col] : 0.f;
      #pragma unroll
      for (int q=0;q<4;++q){
        int row = m0 + wr*64 + mi*16 + g4*4 + q;
        C[(size_t)row*N + col] = acc[mi][ni][q] + bb;
      }
    }
  }
}

// ====== dRoFE attention v6: rope pre-applied in GEMM1 -> pure copy/stage ===
__global__ __launch_bounds__(256) void k_attn(const unsigned short* __restrict__ qkv,
                                              unsigned short* __restrict__ out){
  __shared__ __align__(16) unsigned int kv[PPB][SEQ][68];
  int tid = threadIdx.x;
  int pr = tid / 9, i = tid - pr*9;
  int pair = blockIdx.x*PPB + pr;
  bool act = (pr < PPB) && (pair < NPAIR);
  int b = 0, h = 0;
  const unsigned short* base = qkv;
  if (act){
    b = pair / HEADS; h = pair - b*HEADS;
    base = qkv + (size_t)pair*(SEQ*192);
  }

  float qr[64];
  if (act){
    const u16x8* qp = (const u16x8*)(base + (size_t)i*192);
    const uint4* kp = (const uint4*)(base + (size_t)i*192 + 64);
    const uint4* vp = (const uint4*)(base + (size_t)i*192 + 128);
    #pragma unroll
    for (int t8=0;t8<8;++t8){
      u16x8 qv = qp[t8];
      #pragma unroll
      for (int e=0;e<8;++e) qr[t8*8+e] = b2f(qv[e]);
      *(uint4*)(&kv[pr][i][t8*4])    = kp[t8];   // roped K (copy)
      *(uint4*)(&kv[pr][i][32+t8*4]) = vp[t8];   // raw V (copy)
    }
  }
  __syncthreads();   // K,V staged

  if (!act) return;

  float s[9]; float mx = -1e30f;
  #pragma unroll
  for (int j=0;j<9;++j){
    const uint4* kr = (const uint4*)(&kv[pr][j][0]);
    float acc = 0.f;
    #pragma unroll
    for (int q8=0;q8<8;++q8){
      uint4 kk = kr[q8];
      acc += qr[q8*8+0]*b2f((unsigned short)(kk.x&0xffffu)) + qr[q8*8+1]*b2f((unsigned short)(kk.x>>16));
      acc += qr[q8*8+2]*b2f((unsigned short)(kk.y&0xffffu)) + qr[q8*8+3]*b2f((unsigned short)(kk.y>>16));
      acc += qr[q8*8+4]*b2f((unsigned short)(kk.z&0xffffu)) + qr[q8*8+5]*b2f((unsigned short)(kk.z>>16));
      acc += qr[q8*8+6]*b2f((unsigned short)(kk.w&0xffffu)) + qr[q8*8+7]*b2f((unsigned short)(kk.w>>16));
    }
    s[j] = acc * 0.125f;
    mx = fmaxf(mx, s[j]);
  }
  float den = 0.f;
  #pragma unroll
  for (int j=0;j<9;++j){ s[j] = __expf(s[j]-mx); den += s[j]; }
  float inv = 1.f/den;
  #pragma unroll
  for (int j=0;j<9;++j) s[j] *= inv;

  // PV in two 32-dim halves (o[32] keeps VGPR < 128)
  unsigned short* op = out + (size_t)(b*SEQ+i)*CDIM + h*DH;
  #pragma unroll
  for (int hf=0; hf<2; ++hf){
    float o[32];
    #pragma unroll
    for (int d=0;d<32;++d) o[d]=0.f;
    #pragma unroll
    for (int j=0;j<9;++j){
      float p = s[j];
      const uint4* vr = (const uint4*)(&kv[pr][j][32 + hf*16]);
      #pragma unroll
      for (int q4=0;q4<4;++q4){
        uint4 vv = vr[q4];
        o[q4*8+0] += p*b2f((unsigned short)(vv.x&0xffffu));
        o[q4*8+1] += p*b2f((unsigned short)(vv.x>>16));
        o[q4*8+2] += p*b2f((unsigned short)(vv.y&0xffffu));
        o[q4*8+3] += p*b2f((unsigned short)(vv.y>>16));
        o[q4*8+4] += p*b2f((unsigned short)(vv.z&0xffffu));
        o[q4*8+5] += p*b2f((unsigned short)(vv.z>>16));
        o[q4*8+6] += p*b2f((unsigned short)(vv.w&0xffffu));
        o[q4*8+7] += p*b2f((unsigned short)(vv.w>>16));
      }
    }
    #pragma unroll
    for (int t8=0;t8<4;++t8){
      u16x8 v;
      #pragma unroll
      for (int e=0;e<8;++e) v[e]=f2b(o[t8*8+e]);
      ((u16x8*)op)[hf*4 + t8] = v;
    }
  }
}

extern "C" void kernel_launch(void* const* d_in, const int* in_sizes, int n_in,
                              void* d_out, int out_size, void* d_ws, size_t ws_size,
                              hipStream_t stream){
  const float* x    = (const float*)d_in[0];
  const float* demo = (const float*)d_in[1];
  const float* Wq   = (const float*)d_in[2];
  const float* Wp   = (const float*)d_in[3];
  const float* bp   = (const float*)d_in[4];
  float* outp = (float*)d_out;

  char* wsb = (char*)d_ws;
  unsigned short* xb   = (unsigned short*)wsb;              // x bf16; reused as attn out
  unsigned short* Wq_t = (unsigned short*)(wsb + 56623104); // [2304][768]
  unsigned short* Wp_t = (unsigned short*)(wsb + 60162048); // [768][768]
  float* cs = (float*)(wsb + 61341696);
  float* sn = cs + SEQ*DH;
  unsigned short* qkv  = (unsigned short*)(wsb + 61346304); // head-major [49152][9][192]

  k_prep <<< PREP_BLKS, 256, 0, stream >>> (x, xb, Wq, Wq_t, Wp, Wp_t, cs, sn);

  {
    int nwg = (MROWS/256)*(NQKV/256);   // 144*9 = 1296, %8==0
    k_gemm8p<0><<< nwg, 512, 0, stream >>>
        (xb, Wq_t, qkv, nullptr, demo, cs, sn, MROWS, NQKV, NQKV/256, nwg);
  }

  k_attn <<< (NPAIR + PPB - 1)/PPB, 256, 0, stream >>> (qkv, xb);

  {
    int nwg = (MROWS/256)*(CDIM/128);   // 144*6 = 864, %8==0
    k_gemm2b<<< nwg, 512, 0, stream >>>
        (xb, Wp_t, outp, bp, MROWS, CDIM, CDIM/128, nwg);
  }
}

// Round 14
// 323.073 us; speedup vs baseline: 1.3174x; 1.0248x over previous
//
#include <hip/hip_runtime.h>
#include <cstdint>
#include <cstddef>

typedef __bf16  bf16x8 __attribute__((ext_vector_type(8)));
typedef float   f32x4  __attribute__((ext_vector_type(4)));
typedef unsigned short u16x8 __attribute__((ext_vector_type(8)));
typedef unsigned short u16x4 __attribute__((ext_vector_type(4)));

#define B_SZ  4096
#define SEQ   9
#define CDIM  768
#define HEADS 12
#define DH    64
#define MROWS (B_SZ*SEQ)      // 36864
#define NQKV  (3*CDIM)        // 2304
#define NPAIR (B_SZ*HEADS)    // 49152
#define PPB   28
#define GK    768             // K for both GEMMs
#define NTK   12              // K-tiles for 256^2 kernel (GK/64)
#define NT2   24              // K-tiles for 256x128 kernel (GK/32)

#define AS1 __attribute__((address_space(1)))
#define AS3 __attribute__((address_space(3)))

__device__ inline float b2f(unsigned short u){
  union{unsigned i; float f;} x; x.i = ((unsigned)u)<<16; return x.f;
}
__device__ inline unsigned short f2b(float f){ // RNE fp32->bf16
  unsigned x = __float_as_uint(f);
  return (unsigned short)((x + 0x7fffu + ((x>>16)&1u)) >> 16);
}

// ======= fused prep: x->bf16, LDS-tiled Wq^T, Wp^T, table — 1 launch =======
#define CONV_BLKS (MROWS*CDIM/1024)          // 27648
#define TCQ_BLKS  ((CDIM/64)*(NQKV/64))      // 432
#define TCP_BLKS  ((CDIM/64)*(CDIM/64))      // 144
#define PREP_BLKS (CONV_BLKS+TCQ_BLKS+TCP_BLKS+1)  // 28225

__device__ inline void tconv_tile(const float* __restrict__ in,
                                  unsigned short* __restrict__ out,
                                  int R, int C, int tr, int tc,
                                  float (*tl)[65], int tid){
  int r0 = tr*64, c0 = tc*64;
  int lr = tid >> 4, lc = (tid & 15)*4;
  #pragma unroll
  for (int p=0;p<4;++p){
    float4 v = *(const float4*)(&in[(size_t)(r0+lr+p*16)*C + c0+lc]);
    tl[lr+p*16][lc]=v.x; tl[lr+p*16][lc+1]=v.y; tl[lr+p*16][lc+2]=v.z; tl[lr+p*16][lc+3]=v.w;
  }
  __syncthreads();
  #pragma unroll
  for (int p=0;p<4;++p){
    int oc = lr+p*16;
    u16x4 o;
    o.x = f2b(tl[lc+0][oc]); o.y = f2b(tl[lc+1][oc]);
    o.z = f2b(tl[lc+2][oc]); o.w = f2b(tl[lc+3][oc]);
    *(u16x4*)(&out[(size_t)(c0+oc)*R + r0 + lc]) = o;
  }
}

__global__ __launch_bounds__(256) void k_prep(const float* __restrict__ x,
                                              unsigned short* __restrict__ xb,
                                              const float* __restrict__ Wq,
                                              unsigned short* __restrict__ Wq_t,
                                              const float* __restrict__ Wp,
                                              unsigned short* __restrict__ Wp_t,
                                              float* __restrict__ cs,
                                              float* __restrict__ sn){
  __shared__ float tl[64][65];
  int blk = blockIdx.x, tid = threadIdx.x;
  if (blk < CONV_BLKS){
    int t = blk*256 + tid;
    float4 v = ((const float4*)x)[t];
    u16x4 o; o.x=f2b(v.x); o.y=f2b(v.y); o.z=f2b(v.z); o.w=f2b(v.w);
    ((u16x4*)xb)[t] = o;
  } else if (blk < CONV_BLKS+TCQ_BLKS){
    int b2 = blk - CONV_BLKS;
    tconv_tile(Wq, Wq_t, CDIM, NQKV, b2/36, b2%36, tl, tid);
  } else if (blk < CONV_BLKS+TCQ_BLKS+TCP_BLKS){
    int b3 = blk - CONV_BLKS - TCQ_BLKS;
    tconv_tile(Wp, Wp_t, CDIM, CDIM, b3/12, b3%12, tl, tid);
  } else {
    for (int t=tid; t<SEQ*DH; t+=256){
      const float blo[9] = {1.f,4.f,8.f,10.f,12.f,30.f,1.f,8.f,1.f};
      const float bhi[9] = {4.f,8.f,10.f,12.f,30.f,45.f,8.f,30.f,45.f};
      int n = t / DH, d = t - n*DH;
      int f = (d < 32) ? (d>>1) : ((d-32)>>1);
      float freq = 3.14159265358979f * (1.0f + (4.0f/15.0f)*(float)f);
      float band = (d < 32) ? blo[n] : bhi[n];
      float ang = band * freq;
      cs[t] = cosf(ang);
      sn[t] = sinf(ang);
    }
  }
}

// ---- shared GEMM phase machinery ----
#define GLOAD(SRC, LDSOFF) \
  __builtin_amdgcn_global_load_lds((const AS1 void*)(SRC), \
      (AS3 void*)(smem + (LDSOFF) + (w<<10)), 16, 0, 0)

#define PHASE_MID  do{ __builtin_amdgcn_s_barrier(); \
  asm volatile("s_waitcnt lgkmcnt(0)" ::: "memory"); \
  __builtin_amdgcn_sched_barrier(0); \
  __builtin_amdgcn_s_setprio(1); }while(0)
#define PHASE_END  do{ __builtin_amdgcn_s_setprio(0); \
  __builtin_amdgcn_s_barrier(); }while(0)

// ====== GEMM1: 256x256, BK=64, 4 balanced phases per K-tile (R4 best) ======
// Epilogue applies dRoFE rope via __shfl_xor; tables in LDS as float2 with
// row stride 65 (odd AND >= 64: no overlap, uniform bank coverage).
#define RD_A(SLOT, H) do{ _Pragma("unroll") \
  for (int m=0;m<4;++m) aQ[m] = *(const bf16x8*)((SLOT) + aRd + ((H)*4+m)*1024); }while(0)
#define RD_B(SLOT) do{ _Pragma("unroll") \
  for (int n=0;n<4;++n) bR[n] = *(const bf16x8*)((SLOT) + bRd + n*1024); }while(0)
#define MFMA_Q(H) do{ _Pragma("unroll") \
  for (int m=0;m<4;++m){ _Pragma("unroll") \
    for (int n=0;n<4;++n) \
      acc[(H)*4+m][n] = __builtin_amdgcn_mfma_f32_16x16x32_bf16(aQ[m], bR[n], acc[(H)*4+m][n], 0,0,0); } }while(0)

#define TILE_BODY(T, DB) do{ \
  const char* aS0 = smem + (DB)*16384; \
  const char* aS1 = smem + ((DB)+1)*16384; \
  const char* bS0 = smem + 65536 + (DB)*16384; \
  const char* bS1 = smem + 65536 + ((DB)+1)*16384; \
  int u1=(T)+1; if(u1>NTK-1)u1=NTK-1; int u2=(T)+2; if(u2>NTK-1)u2=NTK-1; \
  size_t o1=(size_t)u1*64+32, o2a=(size_t)u2*64, o2b=o2a+32; \
  /* P1: A mi0-3 k0, B k0; stage B1(t+1) */ \
  RD_A(aS0,0); RD_B(bS0); \
  GLOAD(bSrc0+o1, 65536 + (3-(DB))*16384); \
  GLOAD(bSrc1+o1, 65536 + (3-(DB))*16384 + 8192); \
  PHASE_MID; MFMA_Q(0); PHASE_END; \
  /* P2: A mi4-7 k0; stage A0(t+2) */ \
  RD_A(aS0,1); \
  GLOAD(aSrc0+o2a, (DB)*16384); \
  GLOAD(aSrc1+o2a, (DB)*16384 + 8192); \
  PHASE_MID; MFMA_Q(1); PHASE_END; \
  /* P3: A mi0-3 k1, B k1; stage B0(t+2) */ \
  RD_A(aS1,0); RD_B(bS1); \
  GLOAD(bSrc0+o2a, 65536 + (DB)*16384); \
  GLOAD(bSrc1+o2a, 65536 + (DB)*16384 + 8192); \
  PHASE_MID; MFMA_Q(0); PHASE_END; \
  /* P4: A mi4-7 k1; stage A1(t+2); vmcnt(6) */ \
  RD_A(aS1,1); \
  GLOAD(aSrc0+o2b, ((DB)+1)*16384); \
  GLOAD(aSrc1+o2b, ((DB)+1)*16384 + 8192); \
  PHASE_MID; MFMA_Q(1); \
  __builtin_amdgcn_s_setprio(0); \
  asm volatile("s_waitcnt vmcnt(6)" ::: "memory"); \
  __builtin_amdgcn_s_barrier(); }while(0)

template<int WRITE_F32>
__global__ __launch_bounds__(512, 2) void k_gemm8p(const unsigned short* __restrict__ A,
                                                   const unsigned short* __restrict__ Bt,
                                                   void* __restrict__ Cout,
                                                   const float* __restrict__ bias,
                                                   const float* __restrict__ demo,
                                                   const float* __restrict__ cs,
                                                   const float* __restrict__ sn,
                                                   int M, int N, int NTN, int NWG){
  __shared__ char smem[131072];   // A ring 4x16KB | B ring 4x16KB
  int wg = blockIdx.x;
  int cpx = NWG >> 3;
  int swz = (wg & 7)*cpx + (wg >> 3);          // bijective (NWG%8==0)
  int bm = swz / NTN, bn = swz - bm*NTN;
  int m0 = bm << 8, n0 = bn << 8;

  int tid = threadIdx.x;
  int w = tid >> 6, lane = tid & 63;
  int r = lane & 15, g4 = lane >> 4;
  int wr = w >> 2, wc = w & 3;

  // st_16x32 read-side: 16B-granule g4 ^= 2*row_bit3 (verified 0-conflict)
  int seg = g4 ^ (((r >> 3) & 1) << 1);
  int aRd = (wr*128 + r)*64 + seg*16;
  int bRd = (wc*64  + r)*64 + seg*16;

  // staging side (pre-swizzled global source; linear LDS dest)
  int srow = tid >> 2;
  int gsw  = (tid & 3) ^ (((tid >> 5) & 1) << 1);
  const unsigned short* aSrc0 = A  + (size_t)(m0 + srow)*GK + gsw*8;
  const unsigned short* aSrc1 = aSrc0 + (size_t)128*GK;
  const unsigned short* bSrc0 = Bt + (size_t)(n0 + srow)*GK + gsw*8;
  const unsigned short* bSrc1 = bSrc0 + (size_t)128*GK;

  const f32x4 fz = {0.f,0.f,0.f,0.f};
  f32x4 acc[8][4];
  #pragma unroll
  for (int mi=0;mi<8;++mi)
    #pragma unroll
    for (int ni=0;ni<4;++ni) acc[mi][ni] = fz;
  bf16x8 aQ[4], bR[4];

  // ---- prologue: 7 half-tiles ----
  GLOAD(aSrc0+ 0,     0); GLOAD(aSrc1+ 0,  8192);
  GLOAD(bSrc0+ 0, 65536); GLOAD(bSrc1+ 0, 65536+ 8192);
  GLOAD(aSrc0+32, 16384); GLOAD(aSrc1+32, 16384+8192);
  GLOAD(bSrc0+32, 65536+16384); GLOAD(bSrc1+32, 65536+16384+8192);
  GLOAD(aSrc0+64, 32768); GLOAD(aSrc1+64, 32768+8192);
  GLOAD(bSrc0+64, 65536+32768); GLOAD(bSrc1+64, 65536+32768+8192);
  GLOAD(aSrc0+96, 49152); GLOAD(aSrc1+96, 49152+8192);
  asm volatile("s_waitcnt vmcnt(6)" ::: "memory");
  __builtin_amdgcn_s_barrier();

  #pragma unroll 1
  for (int tt=0; tt<NTK; tt+=2){
    TILE_BODY(tt,   0);
    TILE_BODY(tt+1, 2);
  }
  asm volatile("s_waitcnt vmcnt(0)" ::: "memory");

  // ---- epilogue: C/D layout col=lane&15, row=(lane>>4)*4+q ----
  if (WRITE_F32){
    #pragma unroll
    for (int mi=0;mi<8;++mi){
      #pragma unroll
      for (int ni=0;ni<4;++ni){
        int col = n0 + wc*64 + ni*16 + r;
        float bb = bias ? bias[col] : 0.f;
        #pragma unroll
        for (int q=0;q<4;++q){
          int row = m0 + wr*128 + mi*16 + g4*4 + q;
          ((float*)Cout)[(size_t)row*N + col] = acc[mi][ni][q] + bb;
        }
      }
    }
  } else {
    // K-loop LDS is dead; stage rope tables there.
    // csn2[ii*65+d]: (cs,sn) float2 pairs; stride 65 (>=64, odd) -> rows
    // don't overlap (R13 bug: stride 41 < 64 corrupted the table) and
    // ii-groups land at distinct bank shifts.
    float2* csn2 = (float2*)smem;              // [9*65 = 585] = 4680 B
    float2* sdm2 = (float2*)(smem + 8192);     // [32] demo pairs bb0..bb0+31
    int bb0 = m0 / 9;
    __builtin_amdgcn_s_barrier();              // all waves done with K-loop LDS
    for (int t = tid; t < 576; t += 512){
      int iit = t >> 6, dt = t & 63;
      csn2[iit*65 + dt] = make_float2(cs[t], sn[t]);
    }
    if (tid < 32){
      int gi = bb0 + tid;
      float2 v = make_float2(0.f, 0.f);
      if (gi < B_SZ) v = make_float2(demo[2*gi], demo[2*gi+1]);
      sdm2[tid] = v;
    }
    __syncthreads();

    #pragma unroll
    for (int mi=0;mi<8;++mi){
      #pragma unroll
      for (int q=0;q<4;++q){
        int row = m0 + wr*128 + mi*16 + g4*4 + q;
        int bb = row / 9;
        int ii = row - bb*9;
        float2 ag = sdm2[bb - bb0];            // broadcast (uniform per group)
        size_t rowoff = (size_t)bb*20736 + (size_t)ii*192;
        #pragma unroll
        for (int ni=0;ni<4;++ni){
          int col = n0 + wc*64 + ni*16 + r;
          int which = (col >= 1536) ? 2 : (col >= 768 ? 1 : 0);
          int rem = col - which*768;
          int h = rem >> 6, d = rem & 63;
          float val = acc[mi][ni][q];
          if (which < 2){                      // wave-uniform branch
            float pv = __shfl_xor(val, 1);     // partner element (d^1)
            float2 cv = csn2[ii*65 + d];
            float ev = ag.x*val*cv.x - ag.y*pv*cv.y;  // even d
            float ov = ag.x*val*cv.x + ag.y*pv*cv.y;  // odd d
            val = (d & 1) ? ov : ev;
          }
          ((unsigned short*)Cout)[rowoff + h*1728 + which*64 + d] = f2b(val);
        }
      }
    }
  }
}

// ============ GEMM2: 256x128, BK=32, 3-slot ring, 2 blocks/CU ============
#define TILE2(T, SL, SP) do{ \
  const char* aS = smem + (SL)*16384; \
  const char* bS = smem + 49152 + (SL)*8192; \
  int u2=(T)+2; if(u2>NT2-1)u2=NT2-1; size_t o2=(size_t)u2*32; \
  _Pragma("unroll") for (int m=0;m<4;++m) aQ[m] = *(const bf16x8*)(aS + aRd + m*1024); \
  _Pragma("unroll") for (int n=0;n<4;++n) bR[n] = *(const bf16x8*)(bS + bRd + n*1024); \
  GLOAD(aSrc0+o2, (SP)*16384); \
  GLOAD(aSrc1+o2, (SP)*16384 + 8192); \
  GLOAD(bSrc +o2, 49152 + (SP)*8192); \
  PHASE_MID; \
  _Pragma("unroll") for (int m=0;m<4;++m){ _Pragma("unroll") for (int n=0;n<4;++n) \
    acc[m][n] = __builtin_amdgcn_mfma_f32_16x16x32_bf16(aQ[m], bR[n], acc[m][n], 0,0,0); } \
  __builtin_amdgcn_s_setprio(0); \
  asm volatile("s_waitcnt vmcnt(3)" ::: "memory"); \
  __builtin_amdgcn_s_barrier(); }while(0)

__global__ __launch_bounds__(512, 4) void k_gemm2b(const unsigned short* __restrict__ A,
                                                   const unsigned short* __restrict__ Bt,
                                                   float* __restrict__ C,
                                                   const float* __restrict__ bias,
                                                   int M, int N, int NTN, int NWG){
  __shared__ char smem[73728];   // A 3x16KB | B 3x8KB
  int wg = blockIdx.x;
  int cpx = NWG >> 3;
  int swz = (wg & 7)*cpx + (wg >> 3);
  int bm = swz / NTN, bn = swz - bm*NTN;
  int m0 = bm << 8, n0 = bn << 7;

  int tid = threadIdx.x;
  int w = tid >> 6, lane = tid & 63;
  int r = lane & 15, g4 = lane >> 4;
  int wr = w >> 1, wc = w & 1;

  int seg = g4 ^ (((r >> 3) & 1) << 1);
  int aRd = (wr*64 + r)*64 + seg*16;
  int bRd = (wc*64 + r)*64 + seg*16;

  int srow = tid >> 2;
  int gsw  = (tid & 3) ^ (((tid >> 5) & 1) << 1);
  const unsigned short* aSrc0 = A  + (size_t)(m0 + srow)*GK + gsw*8;
  const unsigned short* aSrc1 = aSrc0 + (size_t)128*GK;
  const unsigned short* bSrc  = Bt + (size_t)(n0 + srow)*GK + gsw*8;

  const f32x4 fz = {0.f,0.f,0.f,0.f};
  f32x4 acc[4][4];
  #pragma unroll
  for (int m=0;m<4;++m)
    #pragma unroll
    for (int n=0;n<4;++n) acc[m][n] = fz;
  bf16x8 aQ[4], bR[4];

  GLOAD(aSrc0+ 0, 0);     GLOAD(aSrc1+ 0, 8192);       GLOAD(bSrc+ 0, 49152);
  GLOAD(aSrc0+32, 16384); GLOAD(aSrc1+32, 16384+8192); GLOAD(bSrc+32, 49152+8192);
  asm volatile("s_waitcnt vmcnt(3)" ::: "memory");
  __builtin_amdgcn_s_barrier();

  #pragma unroll 1
  for (int tt=0; tt<NT2; tt+=3){
    TILE2(tt,   0, 2);
    TILE2(tt+1, 1, 0);
    TILE2(tt+2, 2, 1);
  }
  asm volatile("s_waitcnt vmcnt(0)" ::: "memory");

  #pragma unroll
  for (int mi=0;mi<4;++mi){
    #pragma unroll
    for (int ni=0;ni<4;++ni){
      int col = n0 + wc*64 + ni*16 + r;
      float bb = bias ? bias[col] : 0.f;
      #pragma unroll
      for (int q=0;q<4;++q){
        int row = m0 + wr*64 + mi*16 + g4*4 + q;
        C[(size_t)row*N + col] = acc[mi][ni][q] + bb;
      }
    }
  }
}

// ====== dRoFE attention v6: rope pre-applied in GEMM1 -> pure copy/stage ===
__global__ __launch_bounds__(256) void k_attn(const unsigned short* __restrict__ qkv,
                                              unsigned short* __restrict__ out){
  __shared__ __align__(16) unsigned int kv[PPB][SEQ][68];
  int tid = threadIdx.x;
  int pr = tid / 9, i = tid - pr*9;
  int pair = blockIdx.x*PPB + pr;
  bool act = (pr < PPB) && (pair < NPAIR);
  int b = 0, h = 0;
  const unsigned short* base = qkv;
  if (act){
    b = pair / HEADS; h = pair - b*HEADS;
    base = qkv + (size_t)pair*(SEQ*192);
  }

  float qr[64];
  if (act){
    const u16x8* qp = (const u16x8*)(base + (size_t)i*192);
    const uint4* kp = (const uint4*)(base + (size_t)i*192 + 64);
    const uint4* vp = (const uint4*)(base + (size_t)i*192 + 128);
    #pragma unroll
    for (int t8=0;t8<8;++t8){
      u16x8 qv = qp[t8];
      #pragma unroll
      for (int e=0;e<8;++e) qr[t8*8+e] = b2f(qv[e]);
      *(uint4*)(&kv[pr][i][t8*4])    = kp[t8];   // roped K (copy)
      *(uint4*)(&kv[pr][i][32+t8*4]) = vp[t8];   // raw V (copy)
    }
  }
  __syncthreads();   // K,V staged

  if (!act) return;

  float s[9]; float mx = -1e30f;
  #pragma unroll
  for (int j=0;j<9;++j){
    const uint4* kr = (const uint4*)(&kv[pr][j][0]);
    float acc = 0.f;
    #pragma unroll
    for (int q8=0;q8<8;++q8){
      uint4 kk = kr[q8];
      acc += qr[q8*8+0]*b2f((unsigned short)(kk.x&0xffffu)) + qr[q8*8+1]*b2f((unsigned short)(kk.x>>16));
      acc += qr[q8*8+2]*b2f((unsigned short)(kk.y&0xffffu)) + qr[q8*8+3]*b2f((unsigned short)(kk.y>>16));
      acc += qr[q8*8+4]*b2f((unsigned short)(kk.z&0xffffu)) + qr[q8*8+5]*b2f((unsigned short)(kk.z>>16));
      acc += qr[q8*8+6]*b2f((unsigned short)(kk.w&0xffffu)) + qr[q8*8+7]*b2f((unsigned short)(kk.w>>16));
    }
    s[j] = acc * 0.125f;
    mx = fmaxf(mx, s[j]);
  }
  float den = 0.f;
  #pragma unroll
  for (int j=0;j<9;++j){ s[j] = __expf(s[j]-mx); den += s[j]; }
  float inv = 1.f/den;
  #pragma unroll
  for (int j=0;j<9;++j) s[j] *= inv;

  // PV in two 32-dim halves (o[32] keeps VGPR < 128)
  unsigned short* op = out + (size_t)(b*SEQ+i)*CDIM + h*DH;
  #pragma unroll
  for (int hf=0; hf<2; ++hf){
    float o[32];
    #pragma unroll
    for (int d=0;d<32;++d) o[d]=0.f;
    #pragma unroll
    for (int j=0;j<9;++j){
      float p = s[j];
      const uint4* vr = (const uint4*)(&kv[pr][j][32 + hf*16]);
      #pragma unroll
      for (int q4=0;q4<4;++q4){
        uint4 vv = vr[q4];
        o[q4*8+0] += p*b2f((unsigned short)(vv.x&0xffffu));
        o[q4*8+1] += p*b2f((unsigned short)(vv.x>>16));
        o[q4*8+2] += p*b2f((unsigned short)(vv.y&0xffffu));
        o[q4*8+3] += p*b2f((unsigned short)(vv.y>>16));
        o[q4*8+4] += p*b2f((unsigned short)(vv.z&0xffffu));
        o[q4*8+5] += p*b2f((unsigned short)(vv.z>>16));
        o[q4*8+6] += p*b2f((unsigned short)(vv.w&0xffffu));
        o[q4*8+7] += p*b2f((unsigned short)(vv.w>>16));
      }
    }
    #pragma unroll
    for (int t8=0;t8<4;++t8){
      u16x8 v;
      #pragma unroll
      for (int e=0;e<8;++e) v[e]=f2b(o[t8*8+e]);
      ((u16x8*)op)[hf*4 + t8] = v;
    }
  }
}

extern "C" void kernel_launch(void* const* d_in, const int* in_sizes, int n_in,
                              void* d_out, int out_size, void* d_ws, size_t ws_size,
                              hipStream_t stream){
  const float* x    = (const float*)d_in[0];
  const float* demo = (const float*)d_in[1];
  const float* Wq   = (const float*)d_in[2];
  const float* Wp   = (const float*)d_in[3];
  const float* bp   = (const float*)d_in[4];
  float* outp = (float*)d_out;

  char* wsb = (char*)d_ws;
  unsigned short* xb   = (unsigned short*)wsb;              // x bf16; reused as attn out
  unsigned short* Wq_t = (unsigned short*)(wsb + 56623104); // [2304][768]
  unsigned short* Wp_t = (unsigned short*)(wsb + 60162048); // [768][768]
  float* cs = (float*)(wsb + 61341696);
  float* sn = cs + SEQ*DH;
  unsigned short* qkv  = (unsigned short*)(wsb + 61346304); // head-major [49152][9][192]

  k_prep <<< PREP_BLKS, 256, 0, stream >>> (x, xb, Wq, Wq_t, Wp, Wp_t, cs, sn);

  {
    int nwg = (MROWS/256)*(NQKV/256);   // 144*9 = 1296, %8==0
    k_gemm8p<0><<< nwg, 512, 0, stream >>>
        (xb, Wq_t, qkv, nullptr, demo, cs, sn, MROWS, NQKV, NQKV/256, nwg);
  }

  k_attn <<< (NPAIR + PPB - 1)/PPB, 256, 0, stream >>> (qkv, xb);

  {
    int nwg = (MROWS/256)*(CDIM/128);   // 144*6 = 864, %8==0
    k_gemm2b<<< nwg, 512, 0, stream >>>
        (xb, Wp_t, outp, bp, MROWS, CDIM, CDIM/128, nwg);
  }
}

// Round 15
// 289.350 us; speedup vs baseline: 1.4709x; 1.1165x over previous
//
#include <hip/hip_runtime.h>
#include <cstdint>
#include <cstddef>

typedef __bf16  bf16x8 __attribute__((ext_vector_type(8)));
typedef float   f32x4  __attribute__((ext_vector_type(4)));
typedef unsigned short u16x8 __attribute__((ext_vector_type(8)));
typedef unsigned short u16x4 __attribute__((ext_vector_type(4)));

#define B_SZ  4096
#define SEQ   9
#define CDIM  768
#define HEADS 12
#define DH    64
#define MROWS (B_SZ*SEQ)      // 36864
#define NQKV  (3*CDIM)        // 2304
#define NPAIR (B_SZ*HEADS)    // 49152
#define PPB   28
#define GK    768             // K for both GEMMs
#define NTK   12              // K-tiles for 256^2 kernel (GK/64)
#define NT2   24              // K-tiles for 256x128 kernel (GK/32)

#define AS1 __attribute__((address_space(1)))
#define AS3 __attribute__((address_space(3)))

__device__ inline float b2f(unsigned short u){
  union{unsigned i; float f;} x; x.i = ((unsigned)u)<<16; return x.f;
}
__device__ inline unsigned short f2b(float f){ // RNE fp32->bf16
  unsigned x = __float_as_uint(f);
  return (unsigned short)((x + 0x7fffu + ((x>>16)&1u)) >> 16);
}

// ======= fused prep: x->bf16, LDS-tiled Wq^T, Wp^T, table — 1 launch =======
#define CONV_BLKS (MROWS*CDIM/1024)          // 27648
#define TCQ_BLKS  ((CDIM/64)*(NQKV/64))      // 432
#define TCP_BLKS  ((CDIM/64)*(CDIM/64))      // 144
#define PREP_BLKS (CONV_BLKS+TCQ_BLKS+TCP_BLKS+1)  // 28225

__device__ inline void tconv_tile(const float* __restrict__ in,
                                  unsigned short* __restrict__ out,
                                  int R, int C, int tr, int tc,
                                  float (*tl)[65], int tid){
  int r0 = tr*64, c0 = tc*64;
  int lr = tid >> 4, lc = (tid & 15)*4;
  #pragma unroll
  for (int p=0;p<4;++p){
    float4 v = *(const float4*)(&in[(size_t)(r0+lr+p*16)*C + c0+lc]);
    tl[lr+p*16][lc]=v.x; tl[lr+p*16][lc+1]=v.y; tl[lr+p*16][lc+2]=v.z; tl[lr+p*16][lc+3]=v.w;
  }
  __syncthreads();
  #pragma unroll
  for (int p=0;p<4;++p){
    int oc = lr+p*16;
    u16x4 o;
    o.x = f2b(tl[lc+0][oc]); o.y = f2b(tl[lc+1][oc]);
    o.z = f2b(tl[lc+2][oc]); o.w = f2b(tl[lc+3][oc]);
    *(u16x4*)(&out[(size_t)(c0+oc)*R + r0 + lc]) = o;
  }
}

__global__ __launch_bounds__(256) void k_prep(const float* __restrict__ x,
                                              unsigned short* __restrict__ xb,
                                              const float* __restrict__ Wq,
                                              unsigned short* __restrict__ Wq_t,
                                              const float* __restrict__ Wp,
                                              unsigned short* __restrict__ Wp_t,
                                              float* __restrict__ cs,
                                              float* __restrict__ sn){
  __shared__ float tl[64][65];
  int blk = blockIdx.x, tid = threadIdx.x;
  if (blk < CONV_BLKS){
    int t = blk*256 + tid;
    float4 v = ((const float4*)x)[t];
    u16x4 o; o.x=f2b(v.x); o.y=f2b(v.y); o.z=f2b(v.z); o.w=f2b(v.w);
    ((u16x4*)xb)[t] = o;
  } else if (blk < CONV_BLKS+TCQ_BLKS){
    int b2 = blk - CONV_BLKS;
    tconv_tile(Wq, Wq_t, CDIM, NQKV, b2/36, b2%36, tl, tid);
  } else if (blk < CONV_BLKS+TCQ_BLKS+TCP_BLKS){
    int b3 = blk - CONV_BLKS - TCQ_BLKS;
    tconv_tile(Wp, Wp_t, CDIM, CDIM, b3/12, b3%12, tl, tid);
  } else {
    for (int t=tid; t<SEQ*DH; t+=256){
      const float blo[9] = {1.f,4.f,8.f,10.f,12.f,30.f,1.f,8.f,1.f};
      const float bhi[9] = {4.f,8.f,10.f,12.f,30.f,45.f,8.f,30.f,45.f};
      int n = t / DH, d = t - n*DH;
      int f = (d < 32) ? (d>>1) : ((d-32)>>1);
      float freq = 3.14159265358979f * (1.0f + (4.0f/15.0f)*(float)f);
      float band = (d < 32) ? blo[n] : bhi[n];
      float ang = band * freq;
      cs[t] = cosf(ang);
      sn[t] = sinf(ang);
    }
  }
}

// ---- shared GEMM phase machinery ----
#define GLOAD(SRC, LDSOFF) \
  __builtin_amdgcn_global_load_lds((const AS1 void*)(SRC), \
      (AS3 void*)(smem + (LDSOFF) + (w<<10)), 16, 0, 0)

#define PHASE_MID  do{ __builtin_amdgcn_s_barrier(); \
  asm volatile("s_waitcnt lgkmcnt(0)" ::: "memory"); \
  __builtin_amdgcn_sched_barrier(0); \
  __builtin_amdgcn_s_setprio(1); }while(0)
#define PHASE_END  do{ __builtin_amdgcn_s_setprio(0); \
  __builtin_amdgcn_s_barrier(); }while(0)

// ====== GEMM1: 256x256, BK=64, 4 balanced phases per K-tile (R4 best) ======
// Epilogue specialized on block-uniform which = bn/3 (256-col tiles never
// straddle q/k/v boundaries): V-blocks take a plain store path (no tables,
// no barriers); q/k blocks take one uniform rope path (d = ni*16+r).
#define RD_A(SLOT, H) do{ _Pragma("unroll") \
  for (int m=0;m<4;++m) aQ[m] = *(const bf16x8*)((SLOT) + aRd + ((H)*4+m)*1024); }while(0)
#define RD_B(SLOT) do{ _Pragma("unroll") \
  for (int n=0;n<4;++n) bR[n] = *(const bf16x8*)((SLOT) + bRd + n*1024); }while(0)
#define MFMA_Q(H) do{ _Pragma("unroll") \
  for (int m=0;m<4;++m){ _Pragma("unroll") \
    for (int n=0;n<4;++n) \
      acc[(H)*4+m][n] = __builtin_amdgcn_mfma_f32_16x16x32_bf16(aQ[m], bR[n], acc[(H)*4+m][n], 0,0,0); } }while(0)

#define TILE_BODY(T, DB) do{ \
  const char* aS0 = smem + (DB)*16384; \
  const char* aS1 = smem + ((DB)+1)*16384; \
  const char* bS0 = smem + 65536 + (DB)*16384; \
  const char* bS1 = smem + 65536 + ((DB)+1)*16384; \
  int u1=(T)+1; if(u1>NTK-1)u1=NTK-1; int u2=(T)+2; if(u2>NTK-1)u2=NTK-1; \
  size_t o1=(size_t)u1*64+32, o2a=(size_t)u2*64, o2b=o2a+32; \
  /* P1: A mi0-3 k0, B k0; stage B1(t+1) */ \
  RD_A(aS0,0); RD_B(bS0); \
  GLOAD(bSrc0+o1, 65536 + (3-(DB))*16384); \
  GLOAD(bSrc1+o1, 65536 + (3-(DB))*16384 + 8192); \
  PHASE_MID; MFMA_Q(0); PHASE_END; \
  /* P2: A mi4-7 k0; stage A0(t+2) */ \
  RD_A(aS0,1); \
  GLOAD(aSrc0+o2a, (DB)*16384); \
  GLOAD(aSrc1+o2a, (DB)*16384 + 8192); \
  PHASE_MID; MFMA_Q(1); PHASE_END; \
  /* P3: A mi0-3 k1, B k1; stage B0(t+2) */ \
  RD_A(aS1,0); RD_B(bS1); \
  GLOAD(bSrc0+o2a, 65536 + (DB)*16384); \
  GLOAD(bSrc1+o2a, 65536 + (DB)*16384 + 8192); \
  PHASE_MID; MFMA_Q(0); PHASE_END; \
  /* P4: A mi4-7 k1; stage A1(t+2); vmcnt(6) */ \
  RD_A(aS1,1); \
  GLOAD(aSrc0+o2b, ((DB)+1)*16384); \
  GLOAD(aSrc1+o2b, ((DB)+1)*16384 + 8192); \
  PHASE_MID; MFMA_Q(1); \
  __builtin_amdgcn_s_setprio(0); \
  asm volatile("s_waitcnt vmcnt(6)" ::: "memory"); \
  __builtin_amdgcn_s_barrier(); }while(0)

template<int WRITE_F32>
__global__ __launch_bounds__(512, 2) void k_gemm8p(const unsigned short* __restrict__ A,
                                                   const unsigned short* __restrict__ Bt,
                                                   void* __restrict__ Cout,
                                                   const float* __restrict__ bias,
                                                   const float* __restrict__ demo,
                                                   const float* __restrict__ cs,
                                                   const float* __restrict__ sn,
                                                   int M, int N, int NTN, int NWG){
  __shared__ char smem[131072];   // A ring 4x16KB | B ring 4x16KB
  int wg = blockIdx.x;
  int cpx = NWG >> 3;
  int swz = (wg & 7)*cpx + (wg >> 3);          // bijective (NWG%8==0)
  int bm = swz / NTN, bn = swz - bm*NTN;
  int m0 = bm << 8, n0 = bn << 8;

  int tid = threadIdx.x;
  int w = tid >> 6, lane = tid & 63;
  int r = lane & 15, g4 = lane >> 4;
  int wr = w >> 2, wc = w & 3;

  // st_16x32 read-side: 16B-granule g4 ^= 2*row_bit3 (verified 0-conflict)
  int seg = g4 ^ (((r >> 3) & 1) << 1);
  int aRd = (wr*128 + r)*64 + seg*16;
  int bRd = (wc*64  + r)*64 + seg*16;

  // staging side (pre-swizzled global source; linear LDS dest)
  int srow = tid >> 2;
  int gsw  = (tid & 3) ^ (((tid >> 5) & 1) << 1);
  const unsigned short* aSrc0 = A  + (size_t)(m0 + srow)*GK + gsw*8;
  const unsigned short* aSrc1 = aSrc0 + (size_t)128*GK;
  const unsigned short* bSrc0 = Bt + (size_t)(n0 + srow)*GK + gsw*8;
  const unsigned short* bSrc1 = bSrc0 + (size_t)128*GK;

  const f32x4 fz = {0.f,0.f,0.f,0.f};
  f32x4 acc[8][4];
  #pragma unroll
  for (int mi=0;mi<8;++mi)
    #pragma unroll
    for (int ni=0;ni<4;++ni) acc[mi][ni] = fz;
  bf16x8 aQ[4], bR[4];

  // ---- prologue: 7 half-tiles ----
  GLOAD(aSrc0+ 0,     0); GLOAD(aSrc1+ 0,  8192);
  GLOAD(bSrc0+ 0, 65536); GLOAD(bSrc1+ 0, 65536+ 8192);
  GLOAD(aSrc0+32, 16384); GLOAD(aSrc1+32, 16384+8192);
  GLOAD(bSrc0+32, 65536+16384); GLOAD(bSrc1+32, 65536+16384+8192);
  GLOAD(aSrc0+64, 32768); GLOAD(aSrc1+64, 32768+8192);
  GLOAD(bSrc0+64, 65536+32768); GLOAD(bSrc1+64, 65536+32768+8192);
  GLOAD(aSrc0+96, 49152); GLOAD(aSrc1+96, 49152+8192);
  asm volatile("s_waitcnt vmcnt(6)" ::: "memory");
  __builtin_amdgcn_s_barrier();

  #pragma unroll 1
  for (int tt=0; tt<NTK; tt+=2){
    TILE_BODY(tt,   0);
    TILE_BODY(tt+1, 2);
  }
  asm volatile("s_waitcnt vmcnt(0)" ::: "memory");

  // ---- epilogue: C/D layout col=lane&15, row=(lane>>4)*4+q ----
  if (WRITE_F32){
    #pragma unroll
    for (int mi=0;mi<8;++mi){
      #pragma unroll
      for (int ni=0;ni<4;++ni){
        int col = n0 + wc*64 + ni*16 + r;
        float bb = bias ? bias[col] : 0.f;
        #pragma unroll
        for (int q=0;q<4;++q){
          int row = m0 + wr*128 + mi*16 + g4*4 + q;
          ((float*)Cout)[(size_t)row*N + col] = acc[mi][ni][q] + bb;
        }
      }
    }
  } else if (bn >= 6){
    // ---- pure-V blocks: plain head-major store, no tables/barriers ----
    int n0r = n0 - 1536;                         // 0,256,512
    #pragma unroll
    for (int mi=0;mi<8;++mi){
      #pragma unroll
      for (int q=0;q<4;++q){
        int row = m0 + wr*128 + mi*16 + g4*4 + q;
        int bb = row / 9;
        int ii = row - bb*9;
        size_t rowoff = (size_t)bb*20736 + (size_t)ii*192 + 128;   // which*64 = 128
        #pragma unroll
        for (int ni=0;ni<4;++ni){
          int h = (n0r + wc*64 + ni*16) >> 6;    // ni-uniform
          int d = ni*16 + r;
          ((unsigned short*)Cout)[rowoff + h*1728 + d] = f2b(acc[mi][ni][q]);
        }
      }
    }
  } else {
    // ---- q/k blocks: uniform rope path; tables staged in dead K-loop LDS ----
    float2* csn2 = (float2*)smem;              // [9*65], stride 65 (no overlap)
    float2* sdm2 = (float2*)(smem + 8192);     // [32] demo pairs bb0..bb0+31
    int bb0 = m0 / 9;
    __builtin_amdgcn_s_barrier();              // all waves done with K-loop LDS
    for (int t = tid; t < 576; t += 512){
      int iit = t >> 6, dt = t & 63;
      csn2[iit*65 + dt] = make_float2(cs[t], sn[t]);
    }
    if (tid < 32){
      int gi = bb0 + tid;
      float2 v = make_float2(0.f, 0.f);
      if (gi < B_SZ) v = make_float2(demo[2*gi], demo[2*gi+1]);
      sdm2[tid] = v;
    }
    __syncthreads();

    int which = (bn >= 3);
    int n0r = n0 - which*768;                   // 0,256,512
    #pragma unroll
    for (int mi=0;mi<8;++mi){
      #pragma unroll
      for (int q=0;q<4;++q){
        int row = m0 + wr*128 + mi*16 + g4*4 + q;
        int bb = row / 9;
        int ii = row - bb*9;
        float2 ag = sdm2[bb - bb0];
        size_t rowoff = (size_t)bb*20736 + (size_t)ii*192 + which*64;
        #pragma unroll
        for (int ni=0;ni<4;++ni){
          int h = (n0r + wc*64 + ni*16) >> 6;   // ni-uniform
          int d = ni*16 + r;
          float val = acc[mi][ni][q];
          float pv = __shfl_xor(val, 1);        // partner (d^1), same row
          float2 cv = csn2[ii*65 + d];
          float ev = ag.x*val*cv.x - ag.y*pv*cv.y;   // even d
          float ov = ag.x*val*cv.x + ag.y*pv*cv.y;   // odd d
          val = (d & 1) ? ov : ev;
          ((unsigned short*)Cout)[rowoff + h*1728 + d] = f2b(val);
        }
      }
    }
  }
}

// ============ GEMM2: 256x128, BK=32, 3-slot ring, 2 blocks/CU ============
#define TILE2(T, SL, SP) do{ \
  const char* aS = smem + (SL)*16384; \
  const char* bS = smem + 49152 + (SL)*8192; \
  int u2=(T)+2; if(u2>NT2-1)u2=NT2-1; size_t o2=(size_t)u2*32; \
  _Pragma("unroll") for (int m=0;m<4;++m) aQ[m] = *(const bf16x8*)(aS + aRd + m*1024); \
  _Pragma("unroll") for (int n=0;n<4;++n) bR[n] = *(const bf16x8*)(bS + bRd + n*1024); \
  GLOAD(aSrc0+o2, (SP)*16384); \
  GLOAD(aSrc1+o2, (SP)*16384 + 8192); \
  GLOAD(bSrc +o2, 49152 + (SP)*8192); \
  PHASE_MID; \
  _Pragma("unroll") for (int m=0;m<4;++m){ _Pragma("unroll") for (int n=0;n<4;++n) \
    acc[m][n] = __builtin_amdgcn_mfma_f32_16x16x32_bf16(aQ[m], bR[n], acc[m][n], 0,0,0); } \
  __builtin_amdgcn_s_setprio(0); \
  asm volatile("s_waitcnt vmcnt(3)" ::: "memory"); \
  __builtin_amdgcn_s_barrier(); }while(0)

__global__ __launch_bounds__(512, 4) void k_gemm2b(const unsigned short* __restrict__ A,
                                                   const unsigned short* __restrict__ Bt,
                                                   float* __restrict__ C,
                                                   const float* __restrict__ bias,
                                                   int M, int N, int NTN, int NWG){
  __shared__ char smem[73728];   // A 3x16KB | B 3x8KB
  int wg = blockIdx.x;
  int cpx = NWG >> 3;
  int swz = (wg & 7)*cpx + (wg >> 3);
  int bm = swz / NTN, bn = swz - bm*NTN;
  int m0 = bm << 8, n0 = bn << 7;

  int tid = threadIdx.x;
  int w = tid >> 6, lane = tid & 63;
  int r = lane & 15, g4 = lane >> 4;
  int wr = w >> 1, wc = w & 1;

  int seg = g4 ^ (((r >> 3) & 1) << 1);
  int aRd = (wr*64 + r)*64 + seg*16;
  int bRd = (wc*64 + r)*64 + seg*16;

  int srow = tid >> 2;
  int gsw  = (tid & 3) ^ (((tid >> 5) & 1) << 1);
  const unsigned short* aSrc0 = A  + (size_t)(m0 + srow)*GK + gsw*8;
  const unsigned short* aSrc1 = aSrc0 + (size_t)128*GK;
  const unsigned short* bSrc  = Bt + (size_t)(n0 + srow)*GK + gsw*8;

  const f32x4 fz = {0.f,0.f,0.f,0.f};
  f32x4 acc[4][4];
  #pragma unroll
  for (int m=0;m<4;++m)
    #pragma unroll
    for (int n=0;n<4;++n) acc[m][n] = fz;
  bf16x8 aQ[4], bR[4];

  GLOAD(aSrc0+ 0, 0);     GLOAD(aSrc1+ 0, 8192);       GLOAD(bSrc+ 0, 49152);
  GLOAD(aSrc0+32, 16384); GLOAD(aSrc1+32, 16384+8192); GLOAD(bSrc+32, 49152+8192);
  asm volatile("s_waitcnt vmcnt(3)" ::: "memory");
  __builtin_amdgcn_s_barrier();

  #pragma unroll 1
  for (int tt=0; tt<NT2; tt+=3){
    TILE2(tt,   0, 2);
    TILE2(tt+1, 1, 0);
    TILE2(tt+2, 2, 1);
  }
  asm volatile("s_waitcnt vmcnt(0)" ::: "memory");

  #pragma unroll
  for (int mi=0;mi<4;++mi){
    #pragma unroll
    for (int ni=0;ni<4;++ni){
      int col = n0 + wc*64 + ni*16 + r;
      float bb = bias ? bias[col] : 0.f;
      #pragma unroll
      for (int q=0;q<4;++q){
        int row = m0 + wr*64 + mi*16 + g4*4 + q;
        C[(size_t)row*N + col] = acc[mi][ni][q] + bb;
      }
    }
  }
}

// ====== dRoFE attention v6: rope pre-applied in GEMM1 -> pure copy/stage ===
__global__ __launch_bounds__(256) void k_attn(const unsigned short* __restrict__ qkv,
                                              unsigned short* __restrict__ out){
  __shared__ __align__(16) unsigned int kv[PPB][SEQ][68];
  int tid = threadIdx.x;
  int pr = tid / 9, i = tid - pr*9;
  int pair = blockIdx.x*PPB + pr;
  bool act = (pr < PPB) && (pair < NPAIR);
  int b = 0, h = 0;
  const unsigned short* base = qkv;
  if (act){
    b = pair / HEADS; h = pair - b*HEADS;
    base = qkv + (size_t)pair*(SEQ*192);
  }

  float qr[64];
  if (act){
    const u16x8* qp = (const u16x8*)(base + (size_t)i*192);
    const uint4* kp = (const uint4*)(base + (size_t)i*192 + 64);
    const uint4* vp = (const uint4*)(base + (size_t)i*192 + 128);
    #pragma unroll
    for (int t8=0;t8<8;++t8){
      u16x8 qv = qp[t8];
      #pragma unroll
      for (int e=0;e<8;++e) qr[t8*8+e] = b2f(qv[e]);
      *(uint4*)(&kv[pr][i][t8*4])    = kp[t8];   // roped K (copy)
      *(uint4*)(&kv[pr][i][32+t8*4]) = vp[t8];   // raw V (copy)
    }
  }
  __syncthreads();   // K,V staged

  if (!act) return;

  float s[9]; float mx = -1e30f;
  #pragma unroll
  for (int j=0;j<9;++j){
    const uint4* kr = (const uint4*)(&kv[pr][j][0]);
    float acc = 0.f;
    #pragma unroll
    for (int q8=0;q8<8;++q8){
      uint4 kk = kr[q8];
      acc += qr[q8*8+0]*b2f((unsigned short)(kk.x&0xffffu)) + qr[q8*8+1]*b2f((unsigned short)(kk.x>>16));
      acc += qr[q8*8+2]*b2f((unsigned short)(kk.y&0xffffu)) + qr[q8*8+3]*b2f((unsigned short)(kk.y>>16));
      acc += qr[q8*8+4]*b2f((unsigned short)(kk.z&0xffffu)) + qr[q8*8+5]*b2f((unsigned short)(kk.z>>16));
      acc += qr[q8*8+6]*b2f((unsigned short)(kk.w&0xffffu)) + qr[q8*8+7]*b2f((unsigned short)(kk.w>>16));
    }
    s[j] = acc * 0.125f;
    mx = fmaxf(mx, s[j]);
  }
  float den = 0.f;
  #pragma unroll
  for (int j=0;j<9;++j){ s[j] = __expf(s[j]-mx); den += s[j]; }
  float inv = 1.f/den;
  #pragma unroll
  for (int j=0;j<9;++j) s[j] *= inv;

  // PV in two 32-dim halves (o[32] keeps VGPR < 128)
  unsigned short* op = out + (size_t)(b*SEQ+i)*CDIM + h*DH;
  #pragma unroll
  for (int hf=0; hf<2; ++hf){
    float o[32];
    #pragma unroll
    for (int d=0;d<32;++d) o[d]=0.f;
    #pragma unroll
    for (int j=0;j<9;++j){
      float p = s[j];
      const uint4* vr = (const uint4*)(&kv[pr][j][32 + hf*16]);
      #pragma unroll
      for (int q4=0;q4<4;++q4){
        uint4 vv = vr[q4];
        o[q4*8+0] += p*b2f((unsigned short)(vv.x&0xffffu));
        o[q4*8+1] += p*b2f((unsigned short)(vv.x>>16));
        o[q4*8+2] += p*b2f((unsigned short)(vv.y&0xffffu));
        o[q4*8+3] += p*b2f((unsigned short)(vv.y>>16));
        o[q4*8+4] += p*b2f((unsigned short)(vv.z&0xffffu));
        o[q4*8+5] += p*b2f((unsigned short)(vv.z>>16));
        o[q4*8+6] += p*b2f((unsigned short)(vv.w&0xffffu));
        o[q4*8+7] += p*b2f((unsigned short)(vv.w>>16));
      }
    }
    #pragma unroll
    for (int t8=0;t8<4;++t8){
      u16x8 v;
      #pragma unroll
      for (int e=0;e<8;++e) v[e]=f2b(o[t8*8+e]);
      ((u16x8*)op)[hf*4 + t8] = v;
    }
  }
}

extern "C" void kernel_launch(void* const* d_in, const int* in_sizes, int n_in,
                              void* d_out, int out_size, void* d_ws, size_t ws_size,
                              hipStream_t stream){
  const float* x    = (const float*)d_in[0];
  const float* demo = (const float*)d_in[1];
  const float* Wq   = (const float*)d_in[2];
  const float* Wp   = (const float*)d_in[3];
  const float* bp   = (const float*)d_in[4];
  float* outp = (float*)d_out;

  char* wsb = (char*)d_ws;
  unsigned short* xb   = (unsigned short*)wsb;              // x bf16; reused as attn out
  unsigned short* Wq_t = (unsigned short*)(wsb + 56623104); // [2304][768]
  unsigned short* Wp_t = (unsigned short*)(wsb + 60162048); // [768][768]
  float* cs = (float*)(wsb + 61341696);
  float* sn = cs + SEQ*DH;
  unsigned short* qkv  = (unsigned short*)(wsb + 61346304); // head-major [49152][9][192]

  k_prep <<< PREP_BLKS, 256, 0, stream >>> (x, xb, Wq, Wq_t, Wp, Wp_t, cs, sn);

  {
    int nwg = (MROWS/256)*(NQKV/256);   // 144*9 = 1296, %8==0
    k_gemm8p<0><<< nwg, 512, 0, stream >>>
        (xb, Wq_t, qkv, nullptr, demo, cs, sn, MROWS, NQKV, NQKV/256, nwg);
  }

  k_attn <<< (NPAIR + PPB - 1)/PPB, 256, 0, stream >>> (qkv, xb);

  {
    int nwg = (MROWS/256)*(CDIM/128);   // 144*6 = 864, %8==0
    k_gemm2b<<< nwg, 512, 0, stream >>>
        (xb, Wp_t, outp, bp, MROWS, CDIM, CDIM/128, nwg);
  }
}